// Round 2
// baseline (621.980 us; speedup 1.0000x reference)
//
#include <hip/hip_runtime.h>

// GCN encoder: 2x GCNConv (PyG semantics: self-loops, symmetric norm, aggregate at col)
// x:[100000,256] f32, W1:[256,128], b1:[128], W2:[128,128], b2:[128], edge_index:[2,1600000] int
// out:[100000,128] f32
//
// Pipeline: CSR-by-target build (with per-edge weight) -> GEMM1(f32 in, bf16 out)
//           -> agg1(bf16 gather, f32 out, +b1, relu) -> GEMM2 -> agg2 -> out f32.

#define NN 100000
#define NH 128

__device__ __forceinline__ float bf2f(unsigned int u) { return __uint_as_float(u << 16); }
__device__ __forceinline__ unsigned short f2bf(float f) {
    unsigned int u = __float_as_uint(f);
    u = (u + 0x7fffu + ((u >> 16) & 1u)) >> 16;   // RNE
    return (unsigned short)u;
}

// ---------------- CSR build ----------------
__global__ void k_count(const int* __restrict__ col, int* __restrict__ cnt, int E) {
    int e = blockIdx.x * 256 + threadIdx.x;
    if (e < E) atomicAdd(&cnt[col[e]], 1);
}

__global__ void k_dinv(const int* __restrict__ cnt, float* __restrict__ dinv, int n) {
    int i = blockIdx.x * 256 + threadIdx.x;
    if (i < n) dinv[i] = rsqrtf(1.0f + (float)cnt[i]);   // deg = 1 (self-loop) + in-degree
}

__global__ void k_scan_block(const int* __restrict__ in, int* __restrict__ out,
                             int* __restrict__ bsum, int n) {
    __shared__ int s[256];
    int i = blockIdx.x * 256 + threadIdx.x;
    int v = (i < n) ? in[i] : 0;
    s[threadIdx.x] = v;
    __syncthreads();
    for (int off = 1; off < 256; off <<= 1) {
        int t = (threadIdx.x >= off) ? s[threadIdx.x - off] : 0;
        __syncthreads();
        s[threadIdx.x] += t;
        __syncthreads();
    }
    if (i < n) out[i] = s[threadIdx.x] - v;             // exclusive within block
    if (threadIdx.x == 255) bsum[blockIdx.x] = s[255];  // block total
}

__global__ void k_scan_sums(int* bsum, int nb) {  // nb <= 512, single block of 512
    __shared__ int s[512];
    int tid = threadIdx.x;
    int v = (tid < nb) ? bsum[tid] : 0;
    s[tid] = v;
    __syncthreads();
    for (int off = 1; off < 512; off <<= 1) {
        int t = (tid >= off) ? s[tid - off] : 0;
        __syncthreads();
        s[tid] += t;
        __syncthreads();
    }
    if (tid < nb) bsum[tid] = s[tid] - v;               // exclusive block offsets
}

__global__ void k_scan_add(int* __restrict__ off, const int* __restrict__ bsum,
                           const int* __restrict__ cnt, int n) {
    int i = blockIdx.x * 256 + threadIdx.x;
    if (i < n) {
        int o = off[i] + bsum[blockIdx.x];
        off[i] = o;
        if (i == n - 1) off[n] = o + cnt[i];
    }
}

// fill CSR with packed (src, weight) per edge; cur is a zeroed cursor array
__global__ void k_fill(const int* __restrict__ row, const int* __restrict__ col,
                       const int* __restrict__ off, int* __restrict__ cur,
                       const float* __restrict__ dinv, int2* __restrict__ pair, int E) {
    int e = blockIdx.x * 256 + threadIdx.x;
    if (e < E) {
        int c = col[e];
        int s = row[e];
        int slot = off[c] + atomicAdd(&cur[c], 1);
        pair[slot] = make_int2(s, __float_as_int(dinv[s] * dinv[c]));
    }
}

// ---------------- f32 GEMM: C[M,128](bf16) = A[M,K](f32) @ W[K,128](f32) ----------------
// 128x128 tile, 256 threads, thread tile 16 rows x 4 cols. sA stored transposed so
// inner-loop A reads are b128 broadcasts (conflict-free), W reads are b128 full-stride.
template <int K>
__global__ __launch_bounds__(256) void k_gemm(const float* __restrict__ A,
                                              const float* __restrict__ W,
                                              unsigned short* __restrict__ C, int M) {
    __shared__ float sAT[32][132];   // [k][row], stride 132 keeps 16B alignment
    __shared__ float sW[32][128];
    int tid = threadIdx.x;
    int rowBase = blockIdx.x * 128;
    int tr = tid >> 5;   // 0..7 -> rows tr*16..tr*16+15
    int tc = tid & 31;   // cols tc*4..tc*4+3

    float4 acc[16];
#pragma unroll
    for (int i = 0; i < 16; ++i) acc[i] = make_float4(0.f, 0.f, 0.f, 0.f);

    for (int k0 = 0; k0 < K; k0 += 32) {
        // stage A transposed: 128 rows x 32 k
        {
            int r8 = tid >> 3;   // 0..31
            int kg = tid & 7;    // k-group (float4)
#pragma unroll
            for (int p = 0; p < 4; ++p) {
                int rr = r8 + p * 32;
                int gr = rowBase + rr;
                if (gr >= M) gr = M - 1;
                float4 av = *(const float4*)&A[(size_t)gr * K + k0 + kg * 4];
                sAT[kg * 4 + 0][rr] = av.x;
                sAT[kg * 4 + 1][rr] = av.y;
                sAT[kg * 4 + 2][rr] = av.z;
                sAT[kg * 4 + 3][rr] = av.w;
            }
        }
        // stage W: 32 k x 128 cols
#pragma unroll
        for (int p = 0; p < 4; ++p) {
            int kr = (tid >> 5) + p * 8;
            *(float4*)&sW[kr][tc * 4] = *(const float4*)&W[(size_t)(k0 + kr) * 128 + tc * 4];
        }
        __syncthreads();
#pragma unroll
        for (int kk = 0; kk < 32; ++kk) {
            float4 wv = *(const float4*)&sW[kk][tc * 4];
            float4 a4[4];
#pragma unroll
            for (int q = 0; q < 4; ++q) a4[q] = *(const float4*)&sAT[kk][tr * 16 + q * 4];
            const float* aq = (const float*)a4;
#pragma unroll
            for (int i = 0; i < 16; ++i) {
                float a = aq[i];
                acc[i].x += a * wv.x;
                acc[i].y += a * wv.y;
                acc[i].z += a * wv.z;
                acc[i].w += a * wv.w;
            }
        }
        __syncthreads();
    }
#pragma unroll
    for (int i = 0; i < 16; ++i) {
        int r = rowBase + tr * 16 + i;
        if (r < M) {
            ushort4 o;
            o.x = f2bf(acc[i].x);
            o.y = f2bf(acc[i].y);
            o.z = f2bf(acc[i].z);
            o.w = f2bf(acc[i].w);
            *(ushort4*)&C[(size_t)r * 128 + tc * 4] = o;
        }
    }
}

// ---------------- aggregate ----------------
// out[i] = sum_{e: col=i} h[src_e]*w_e + h[i]*dinv[i]^2 + b ; 64 lanes per node, 2 feats/lane.
template <bool RELU>
__global__ __launch_bounds__(256) void k_agg(const unsigned short* __restrict__ hb,
                                             const float* __restrict__ dinv,
                                             const int* __restrict__ off,
                                             const int2* __restrict__ pair,
                                             const float* __restrict__ bias,
                                             float* __restrict__ out, int n) {
    int node = blockIdx.x * 4 + (threadIdx.x >> 6);
    int lane = threadIdx.x & 63;
    if (node >= n) return;
    float di = dinv[node];
    unsigned int us = *(const unsigned int*)(hb + ((size_t)node << 7) + lane * 2);
    float w0 = di * di;
    float a0 = bf2f(us & 0xffffu) * w0;
    float a1 = bf2f(us >> 16) * w0;
    int e0 = off[node], e1 = off[node + 1];
    for (int e = e0; e < e1; ++e) {
        int2 p = pair[e];
        float w = __int_as_float(p.y);
        unsigned int u = *(const unsigned int*)(hb + ((size_t)p.x << 7) + lane * 2);
        a0 += w * bf2f(u & 0xffffu);
        a1 += w * bf2f(u >> 16);
    }
    a0 += bias[lane * 2];
    a1 += bias[lane * 2 + 1];
    if (RELU) {
        a0 = fmaxf(a0, 0.f);
        a1 = fmaxf(a1, 0.f);
    }
    *(float2*)(out + ((size_t)node << 7) + lane * 2) = make_float2(a0, a1);
}

extern "C" void kernel_launch(void* const* d_in, const int* in_sizes, int n_in,
                              void* d_out, int out_size, void* d_ws, size_t ws_size,
                              hipStream_t stream) {
    const float* x  = (const float*)d_in[0];
    const float* W1 = (const float*)d_in[1];
    const float* b1 = (const float*)d_in[2];
    const float* W2 = (const float*)d_in[3];
    const float* b2 = (const float*)d_in[4];
    const int*   ei = (const int*)d_in[5];

    const int n = NN;
    const int E = in_sizes[5] / 2;
    const int* row = ei;        // sources
    const int* col = ei + E;    // targets

    char* ws = (char*)d_ws;
    size_t o = 0;
    auto alloc = [&](size_t bytes) {
        void* p = ws + o;
        o = (o + bytes + 255) & ~(size_t)255;
        return p;
    };
    int*            cnt  = (int*)alloc((size_t)n * 4);
    int*            offs = (int*)alloc((size_t)(n + 1) * 4);
    int*            bsum = (int*)alloc(512 * 4);
    float*          dinv = (float*)alloc((size_t)n * 4);
    int2*           pair = (int2*)alloc((size_t)E * 8);
    unsigned short* bufH = (unsigned short*)alloc((size_t)n * NH * 2);  // bf16 h
    float*          bufG = (float*)alloc((size_t)n * NH * 4);           // f32 g

    int nb = (n + 255) / 256;  // 391

    hipMemsetAsync(cnt, 0, (size_t)n * 4, stream);
    k_count<<<(E + 255) / 256, 256, 0, stream>>>(col, cnt, E);
    k_dinv<<<nb, 256, 0, stream>>>(cnt, dinv, n);
    k_scan_block<<<nb, 256, 0, stream>>>(cnt, offs, bsum, n);
    k_scan_sums<<<1, 512, 0, stream>>>(bsum, nb);
    k_scan_add<<<nb, 256, 0, stream>>>(offs, bsum, cnt, n);
    hipMemsetAsync(cnt, 0, (size_t)n * 4, stream);  // reuse as cursor
    k_fill<<<(E + 255) / 256, 256, 0, stream>>>(row, col, offs, cnt, dinv, pair, E);

    int aggBlocks = (n + 3) / 4;
    // layer 1: h = x@W1 (bf16) ; g = relu(agg(h) + b1) (f32)
    k_gemm<256><<<(n + 127) / 128, 256, 0, stream>>>(x, W1, bufH, n);
    k_agg<true><<<aggBlocks, 256, 0, stream>>>(bufH, dinv, offs, pair, b1, bufG, n);
    // layer 2: h = g@W2 (bf16) ; out = agg(h) + b2 (f32)
    k_gemm<128><<<(n + 127) / 128, 256, 0, stream>>>(bufG, W2, bufH, n);
    k_agg<false><<<aggBlocks, 256, 0, stream>>>(bufH, dinv, offs, pair, b2, (float*)d_out, n);
}

// Round 3
// 442.134 us; speedup vs baseline: 1.4068x; 1.4068x over previous
//
#include <hip/hip_runtime.h>

// GCN encoder: 2x GCNConv (PyG semantics: self-loops, symmetric norm, aggregate at col)
// x:[100000,256] f32, W1:[256,128], b1:[128], W2:[128,128], b2:[128], edge_index:[2,1600000] int
// out:[100000,128] f32
//
// Pipeline: CSR-by-target build (with per-edge weight) -> GEMM1(f32 in, bf16 out)
//           -> agg1(bf16 gather, f32 out, +b1, relu) -> GEMM2 -> agg2 -> out f32.
// agg is latency-bound on the random row gather: 32 lanes/node + 4x manual unroll
// keeps ~8 independent 256B row-gathers in flight per wave.

#define NN 100000
#define NH 128

__device__ __forceinline__ float bf2f(unsigned int u) { return __uint_as_float(u << 16); }
__device__ __forceinline__ unsigned short f2bf(float f) {
    unsigned int u = __float_as_uint(f);
    u = (u + 0x7fffu + ((u >> 16) & 1u)) >> 16;   // RNE
    return (unsigned short)u;
}

// ---------------- CSR build ----------------
__global__ void k_count(const int* __restrict__ col, int* __restrict__ cnt, int E) {
    int e = blockIdx.x * 256 + threadIdx.x;
    if (e < E) atomicAdd(&cnt[col[e]], 1);
}

__global__ void k_dinv(const int* __restrict__ cnt, float* __restrict__ dinv, int n) {
    int i = blockIdx.x * 256 + threadIdx.x;
    if (i < n) dinv[i] = rsqrtf(1.0f + (float)cnt[i]);   // deg = 1 (self-loop) + in-degree
}

__global__ void k_scan_block(const int* __restrict__ in, int* __restrict__ out,
                             int* __restrict__ bsum, int n) {
    __shared__ int s[256];
    int i = blockIdx.x * 256 + threadIdx.x;
    int v = (i < n) ? in[i] : 0;
    s[threadIdx.x] = v;
    __syncthreads();
    for (int off = 1; off < 256; off <<= 1) {
        int t = (threadIdx.x >= off) ? s[threadIdx.x - off] : 0;
        __syncthreads();
        s[threadIdx.x] += t;
        __syncthreads();
    }
    if (i < n) out[i] = s[threadIdx.x] - v;             // exclusive within block
    if (threadIdx.x == 255) bsum[blockIdx.x] = s[255];  // block total
}

__global__ void k_scan_sums(int* bsum, int nb) {  // nb <= 512, single block of 512
    __shared__ int s[512];
    int tid = threadIdx.x;
    int v = (tid < nb) ? bsum[tid] : 0;
    s[tid] = v;
    __syncthreads();
    for (int off = 1; off < 512; off <<= 1) {
        int t = (tid >= off) ? s[tid - off] : 0;
        __syncthreads();
        s[tid] += t;
        __syncthreads();
    }
    if (tid < nb) bsum[tid] = s[tid] - v;               // exclusive block offsets
}

__global__ void k_scan_add(int* __restrict__ off, const int* __restrict__ bsum,
                           const int* __restrict__ cnt, int n) {
    int i = blockIdx.x * 256 + threadIdx.x;
    if (i < n) {
        int o = off[i] + bsum[blockIdx.x];
        off[i] = o;
        if (i == n - 1) off[n] = o + cnt[i];
    }
}

// fill CSR with packed (src, weight) per edge; cur is a zeroed cursor array
__global__ void k_fill(const int* __restrict__ row, const int* __restrict__ col,
                       const int* __restrict__ off, int* __restrict__ cur,
                       const float* __restrict__ dinv, int2* __restrict__ pair, int E) {
    int e = blockIdx.x * 256 + threadIdx.x;
    if (e < E) {
        int c = col[e];
        int s = row[e];
        int slot = off[c] + atomicAdd(&cur[c], 1);
        pair[slot] = make_int2(s, __float_as_int(dinv[s] * dinv[c]));
    }
}

// ---------------- f32 GEMM: C[M,128](bf16) = A[M,K](f32) @ W[K,128](f32) ----------------
// 128x128 tile, 256 threads, thread tile 16 rows x 4 cols. sA stored transposed so
// inner-loop A reads are b128 broadcasts (conflict-free), W reads are b128 full-stride.
template <int K>
__global__ __launch_bounds__(256) void k_gemm(const float* __restrict__ A,
                                              const float* __restrict__ W,
                                              unsigned short* __restrict__ C, int M) {
    __shared__ float sAT[32][132];   // [k][row], stride 132 keeps 16B alignment
    __shared__ float sW[32][128];
    int tid = threadIdx.x;
    int rowBase = blockIdx.x * 128;
    int tr = tid >> 5;   // 0..7 -> rows tr*16..tr*16+15
    int tc = tid & 31;   // cols tc*4..tc*4+3

    float4 acc[16];
#pragma unroll
    for (int i = 0; i < 16; ++i) acc[i] = make_float4(0.f, 0.f, 0.f, 0.f);

    for (int k0 = 0; k0 < K; k0 += 32) {
        // stage A transposed: 128 rows x 32 k
        {
            int r8 = tid >> 3;   // 0..31
            int kg = tid & 7;    // k-group (float4)
#pragma unroll
            for (int p = 0; p < 4; ++p) {
                int rr = r8 + p * 32;
                int gr = rowBase + rr;
                if (gr >= M) gr = M - 1;
                float4 av = *(const float4*)&A[(size_t)gr * K + k0 + kg * 4];
                sAT[kg * 4 + 0][rr] = av.x;
                sAT[kg * 4 + 1][rr] = av.y;
                sAT[kg * 4 + 2][rr] = av.z;
                sAT[kg * 4 + 3][rr] = av.w;
            }
        }
        // stage W: 32 k x 128 cols
#pragma unroll
        for (int p = 0; p < 4; ++p) {
            int kr = (tid >> 5) + p * 8;
            *(float4*)&sW[kr][tc * 4] = *(const float4*)&W[(size_t)(k0 + kr) * 128 + tc * 4];
        }
        __syncthreads();
#pragma unroll
        for (int kk = 0; kk < 32; ++kk) {
            float4 wv = *(const float4*)&sW[kk][tc * 4];
            float4 a4[4];
#pragma unroll
            for (int q = 0; q < 4; ++q) a4[q] = *(const float4*)&sAT[kk][tr * 16 + q * 4];
            const float* aq = (const float*)a4;
#pragma unroll
            for (int i = 0; i < 16; ++i) {
                float a = aq[i];
                acc[i].x += a * wv.x;
                acc[i].y += a * wv.y;
                acc[i].z += a * wv.z;
                acc[i].w += a * wv.w;
            }
        }
        __syncthreads();
    }
#pragma unroll
    for (int i = 0; i < 16; ++i) {
        int r = rowBase + tr * 16 + i;
        if (r < M) {
            ushort4 o;
            o.x = f2bf(acc[i].x);
            o.y = f2bf(acc[i].y);
            o.z = f2bf(acc[i].z);
            o.w = f2bf(acc[i].w);
            *(ushort4*)&C[(size_t)r * 128 + tc * 4] = o;
        }
    }
}

// ---------------- aggregate ----------------
// out[i] = sum_{e: col=i} h[src_e]*w_e + h[i]*dinv[i]^2 + b
// 32 lanes per node (4 feats/lane, uint2=8B), 2 nodes per wave, edge loop unrolled 4x
// so ~8 independent row gathers are in flight per wave.
template <bool RELU>
__global__ __launch_bounds__(256) void k_agg(const unsigned short* __restrict__ hb,
                                             const float* __restrict__ dinv,
                                             const int* __restrict__ off,
                                             const int2* __restrict__ pair,
                                             const float* __restrict__ bias,
                                             float* __restrict__ out, int n) {
    int node = blockIdx.x * 8 + (threadIdx.x >> 5);
    int lane = threadIdx.x & 31;
    if (node >= n) return;
    float di = dinv[node];
    uint2 us = *(const uint2*)(hb + ((size_t)node << 7) + lane * 4);
    float w0 = di * di;
    float a0 = bf2f(us.x & 0xffffu) * w0;
    float a1 = bf2f(us.x >> 16) * w0;
    float a2 = bf2f(us.y & 0xffffu) * w0;
    float a3 = bf2f(us.y >> 16) * w0;
    int e  = off[node];
    int e1 = off[node + 1];
    for (; e + 4 <= e1; e += 4) {
        int2 p0 = pair[e + 0];
        int2 p1 = pair[e + 1];
        int2 p2 = pair[e + 2];
        int2 p3 = pair[e + 3];
        uint2 u0 = *(const uint2*)(hb + ((size_t)p0.x << 7) + lane * 4);
        uint2 u1 = *(const uint2*)(hb + ((size_t)p1.x << 7) + lane * 4);
        uint2 u2 = *(const uint2*)(hb + ((size_t)p2.x << 7) + lane * 4);
        uint2 u3 = *(const uint2*)(hb + ((size_t)p3.x << 7) + lane * 4);
        float w0e = __int_as_float(p0.y);
        float w1e = __int_as_float(p1.y);
        float w2e = __int_as_float(p2.y);
        float w3e = __int_as_float(p3.y);
        a0 += w0e * bf2f(u0.x & 0xffffu); a1 += w0e * bf2f(u0.x >> 16);
        a2 += w0e * bf2f(u0.y & 0xffffu); a3 += w0e * bf2f(u0.y >> 16);
        a0 += w1e * bf2f(u1.x & 0xffffu); a1 += w1e * bf2f(u1.x >> 16);
        a2 += w1e * bf2f(u1.y & 0xffffu); a3 += w1e * bf2f(u1.y >> 16);
        a0 += w2e * bf2f(u2.x & 0xffffu); a1 += w2e * bf2f(u2.x >> 16);
        a2 += w2e * bf2f(u2.y & 0xffffu); a3 += w2e * bf2f(u2.y >> 16);
        a0 += w3e * bf2f(u3.x & 0xffffu); a1 += w3e * bf2f(u3.x >> 16);
        a2 += w3e * bf2f(u3.y & 0xffffu); a3 += w3e * bf2f(u3.y >> 16);
    }
    for (; e < e1; ++e) {
        int2 p = pair[e];
        float w = __int_as_float(p.y);
        uint2 u = *(const uint2*)(hb + ((size_t)p.x << 7) + lane * 4);
        a0 += w * bf2f(u.x & 0xffffu); a1 += w * bf2f(u.x >> 16);
        a2 += w * bf2f(u.y & 0xffffu); a3 += w * bf2f(u.y >> 16);
    }
    float4 b = *(const float4*)&bias[lane * 4];
    a0 += b.x; a1 += b.y; a2 += b.z; a3 += b.w;
    if (RELU) {
        a0 = fmaxf(a0, 0.f); a1 = fmaxf(a1, 0.f);
        a2 = fmaxf(a2, 0.f); a3 = fmaxf(a3, 0.f);
    }
    *(float4*)(out + ((size_t)node << 7) + lane * 4) = make_float4(a0, a1, a2, a3);
}

extern "C" void kernel_launch(void* const* d_in, const int* in_sizes, int n_in,
                              void* d_out, int out_size, void* d_ws, size_t ws_size,
                              hipStream_t stream) {
    const float* x  = (const float*)d_in[0];
    const float* W1 = (const float*)d_in[1];
    const float* b1 = (const float*)d_in[2];
    const float* W2 = (const float*)d_in[3];
    const float* b2 = (const float*)d_in[4];
    const int*   ei = (const int*)d_in[5];

    const int n = NN;
    const int E = in_sizes[5] / 2;
    const int* row = ei;        // sources
    const int* col = ei + E;    // targets

    char* ws = (char*)d_ws;
    size_t o = 0;
    auto alloc = [&](size_t bytes) {
        void* p = ws + o;
        o = (o + bytes + 255) & ~(size_t)255;
        return p;
    };
    int*            cnt  = (int*)alloc((size_t)n * 4);
    int*            offs = (int*)alloc((size_t)(n + 1) * 4);
    int*            bsum = (int*)alloc(512 * 4);
    float*          dinv = (float*)alloc((size_t)n * 4);
    int2*           pair = (int2*)alloc((size_t)E * 8);
    unsigned short* bufH = (unsigned short*)alloc((size_t)n * NH * 2);  // bf16 h
    float*          bufG = (float*)alloc((size_t)n * NH * 4);           // f32 g

    int nb = (n + 255) / 256;  // 391

    hipMemsetAsync(cnt, 0, (size_t)n * 4, stream);
    k_count<<<(E + 255) / 256, 256, 0, stream>>>(col, cnt, E);
    k_dinv<<<nb, 256, 0, stream>>>(cnt, dinv, n);
    k_scan_block<<<nb, 256, 0, stream>>>(cnt, offs, bsum, n);
    k_scan_sums<<<1, 512, 0, stream>>>(bsum, nb);
    k_scan_add<<<nb, 256, 0, stream>>>(offs, bsum, cnt, n);
    hipMemsetAsync(cnt, 0, (size_t)n * 4, stream);  // reuse as cursor
    k_fill<<<(E + 255) / 256, 256, 0, stream>>>(row, col, offs, cnt, dinv, pair, E);

    int aggBlocks = (n + 7) / 8;
    // layer 1: h = x@W1 (bf16) ; g = relu(agg(h) + b1) (f32)
    k_gemm<256><<<(n + 127) / 128, 256, 0, stream>>>(x, W1, bufH, n);
    k_agg<true><<<aggBlocks, 256, 0, stream>>>(bufH, dinv, offs, pair, b1, bufG, n);
    // layer 2: h = g@W2 (bf16) ; out = agg(h) + b2 (f32)
    k_gemm<128><<<(n + 127) / 128, 256, 0, stream>>>(bufG, W2, bufH, n);
    k_agg<false><<<aggBlocks, 256, 0, stream>>>(bufH, dinv, offs, pair, b2, (float*)d_out, n);
}

// Round 4
// 422.129 us; speedup vs baseline: 1.4734x; 1.0474x over previous
//
#include <hip/hip_runtime.h>

// GCN encoder: 2x GCNConv (PyG semantics: self-loops, symmetric norm, aggregate at col)
// x:[100000,256] f32, W1:[256,128], b1:[128], W2:[128,128], b2:[128], edge_index:[2,1600000] int
// out:[100000,128] f32
//
// Pipeline: CSR-by-target build -> MFMA GEMM1 (hi/lo bf16 split, near-f32 accurate, bf16 out)
//           -> agg1(bf16 gather, +b1, relu) -> MFMA GEMM2 -> agg2 -> out f32.

#define NN 100000
#define NH 128

__device__ __forceinline__ float bf2f(unsigned int u) { return __uint_as_float(u << 16); }
__device__ __forceinline__ unsigned short f2bf(float f) {
    unsigned int u = __float_as_uint(f);
    u = (u + 0x7fffu + ((u >> 16) & 1u)) >> 16;   // RNE
    return (unsigned short)u;
}

// ---------------- CSR build ----------------
__global__ void k_count(const int* __restrict__ col, int* __restrict__ cnt, int E) {
    int e = blockIdx.x * 256 + threadIdx.x;
    if (e < E) atomicAdd(&cnt[col[e]], 1);
}

__global__ void k_dinv(const int* __restrict__ cnt, float* __restrict__ dinv, int n) {
    int i = blockIdx.x * 256 + threadIdx.x;
    if (i < n) dinv[i] = rsqrtf(1.0f + (float)cnt[i]);   // deg = 1 (self-loop) + in-degree
}

__global__ void k_scan_block(const int* __restrict__ in, int* __restrict__ out,
                             int* __restrict__ bsum, int n) {
    __shared__ int s[256];
    int i = blockIdx.x * 256 + threadIdx.x;
    int v = (i < n) ? in[i] : 0;
    s[threadIdx.x] = v;
    __syncthreads();
    for (int off = 1; off < 256; off <<= 1) {
        int t = (threadIdx.x >= off) ? s[threadIdx.x - off] : 0;
        __syncthreads();
        s[threadIdx.x] += t;
        __syncthreads();
    }
    if (i < n) out[i] = s[threadIdx.x] - v;             // exclusive within block
    if (threadIdx.x == 255) bsum[blockIdx.x] = s[255];  // block total
}

__global__ void k_scan_sums(int* bsum, int nb) {  // nb <= 512, single block of 512
    __shared__ int s[512];
    int tid = threadIdx.x;
    int v = (tid < nb) ? bsum[tid] : 0;
    s[tid] = v;
    __syncthreads();
    for (int off = 1; off < 512; off <<= 1) {
        int t = (tid >= off) ? s[tid - off] : 0;
        __syncthreads();
        s[tid] += t;
        __syncthreads();
    }
    if (tid < nb) bsum[tid] = s[tid] - v;               // exclusive block offsets
}

__global__ void k_scan_add(int* __restrict__ off, const int* __restrict__ bsum,
                           const int* __restrict__ cnt, int n) {
    int i = blockIdx.x * 256 + threadIdx.x;
    if (i < n) {
        int o = off[i] + bsum[blockIdx.x];
        off[i] = o;
        if (i == n - 1) off[n] = o + cnt[i];
    }
}

// fill CSR with packed (src, weight) per edge; cur is a zeroed cursor array
__global__ void k_fill(const int* __restrict__ row, const int* __restrict__ col,
                       const int* __restrict__ off, int* __restrict__ cur,
                       const float* __restrict__ dinv, int2* __restrict__ pair, int E) {
    int e = blockIdx.x * 256 + threadIdx.x;
    if (e < E) {
        int c = col[e];
        int s = row[e];
        int slot = off[c] + atomicAdd(&cur[c], 1);
        pair[slot] = make_int2(s, __float_as_int(dinv[s] * dinv[c]));
    }
}

// ---------------- W prepass: f32 [K][128] -> transposed bf16 hi/lo [128][K] ----------------
__global__ void k_wprep(const float* __restrict__ W, unsigned short* __restrict__ Thi,
                        unsigned short* __restrict__ Tlo, int K) {
    int idx = blockIdx.x * 256 + threadIdx.x;
    if (idx >= K * 128) return;
    int k = idx >> 7, c = idx & 127;
    float w = W[idx];
    unsigned int u = __float_as_uint(w) & 0xffff0000u;   // truncate hi
    float rem = w - __uint_as_float(u);
    Thi[(size_t)c * K + k] = (unsigned short)(u >> 16);
    Tlo[(size_t)c * K + k] = (unsigned short)(__float_as_uint(rem) >> 16);
}

// ---------------- MFMA GEMM: C[M,128](bf16) = A[M,K](f32) @ W[K,128] ----------------
// Split A and W into bf16 hi+lo; AhBh + AlBh + AhBl ~= f32-accurate.
// Wave = 32 rows x 128 cols (2 A-frags, 8 N-tiles, 16x16x32 MFMA). No LDS:
// A loaded per-lane in fragment order (f32, converted in-register), B frags are
// 16B loads from pre-transposed Wt[col][k] (L2-resident).
template <int K>
__global__ __launch_bounds__(256) void k_gemm_mfma(const float* __restrict__ A,
                                                   const unsigned short* __restrict__ Bhi,
                                                   const unsigned short* __restrict__ Blo,
                                                   unsigned short* __restrict__ C, int M) {
    using bf16x8 = __attribute__((ext_vector_type(8))) short;
    using f32x4  = __attribute__((ext_vector_type(4))) float;
    const int lane = threadIdx.x & 63;
    const int wv   = threadIdx.x >> 6;       // 0..3
    const int r    = lane & 15;              // A-row / B-col / C-col within frag
    const int kb   = lane >> 4;              // k-block 0..3
    const int wrow = blockIdx.x * 128 + wv * 32;

    int row0 = wrow + r;       if (row0 >= M) row0 = M - 1;
    int row1 = wrow + 16 + r;  if (row1 >= M) row1 = M - 1;
    const float* a0p = A + (size_t)row0 * K;
    const float* a1p = A + (size_t)row1 * K;

    f32x4 acc[2][8];
#pragma unroll
    for (int m = 0; m < 2; ++m)
#pragma unroll
        for (int t = 0; t < 8; ++t) acc[m][t] = (f32x4){0.f, 0.f, 0.f, 0.f};

    for (int k0 = 0; k0 < K; k0 += 32) {
        const int kk = k0 + kb * 8;
        bf16x8 ah[2], al[2];
        {
            float4 p0 = *(const float4*)(a0p + kk);
            float4 q0 = *(const float4*)(a0p + kk + 4);
            float4 p1 = *(const float4*)(a1p + kk);
            float4 q1 = *(const float4*)(a1p + kk + 4);
            float av0[8] = {p0.x, p0.y, p0.z, p0.w, q0.x, q0.y, q0.z, q0.w};
            float av1[8] = {p1.x, p1.y, p1.z, p1.w, q1.x, q1.y, q1.z, q1.w};
#pragma unroll
            for (int j = 0; j < 8; ++j) {
                unsigned int u0 = __float_as_uint(av0[j]) & 0xffff0000u;
                float r0 = av0[j] - __uint_as_float(u0);
                ah[0][j] = (short)(u0 >> 16);
                al[0][j] = (short)(__float_as_uint(r0) >> 16);
                unsigned int u1 = __float_as_uint(av1[j]) & 0xffff0000u;
                float r1 = av1[j] - __uint_as_float(u1);
                ah[1][j] = (short)(u1 >> 16);
                al[1][j] = (short)(__float_as_uint(r1) >> 16);
            }
        }
#pragma unroll
        for (int t = 0; t < 8; ++t) {
            const size_t bo = (size_t)(t * 16 + r) * K + kk;
            bf16x8 bh = *(const bf16x8*)(Bhi + bo);
            bf16x8 bl = *(const bf16x8*)(Blo + bo);
#pragma unroll
            for (int m = 0; m < 2; ++m) {
                acc[m][t] = __builtin_amdgcn_mfma_f32_16x16x32_bf16(ah[m], bh, acc[m][t], 0, 0, 0);
                acc[m][t] = __builtin_amdgcn_mfma_f32_16x16x32_bf16(al[m], bh, acc[m][t], 0, 0, 0);
                acc[m][t] = __builtin_amdgcn_mfma_f32_16x16x32_bf16(ah[m], bl, acc[m][t], 0, 0, 0);
            }
        }
    }
    // C/D layout (m89-verified): col = lane&15, row = (lane>>4)*4 + reg
#pragma unroll
    for (int m = 0; m < 2; ++m) {
        int ob = wrow + m * 16 + kb * 4;
#pragma unroll
        for (int t = 0; t < 8; ++t) {
#pragma unroll
            for (int q = 0; q < 4; ++q) {
                int orow = ob + q;
                if (orow < M) C[(size_t)orow * 128 + t * 16 + r] = f2bf(acc[m][t][q]);
            }
        }
    }
}

// ---------------- aggregate ----------------
// out[i] = sum_{e: col=i} h[src_e]*w_e + h[i]*dinv[i]^2 + b
// 32 lanes per node (4 feats/lane, uint2=8B), 2 nodes per wave, edge loop unrolled 4x
// so ~8 independent row gathers are in flight per wave.
template <bool RELU>
__global__ __launch_bounds__(256) void k_agg(const unsigned short* __restrict__ hb,
                                             const float* __restrict__ dinv,
                                             const int* __restrict__ off,
                                             const int2* __restrict__ pair,
                                             const float* __restrict__ bias,
                                             float* __restrict__ out, int n) {
    int node = blockIdx.x * 8 + (threadIdx.x >> 5);
    int lane = threadIdx.x & 31;
    if (node >= n) return;
    float di = dinv[node];
    uint2 us = *(const uint2*)(hb + ((size_t)node << 7) + lane * 4);
    float w0 = di * di;
    float a0 = bf2f(us.x & 0xffffu) * w0;
    float a1 = bf2f(us.x >> 16) * w0;
    float a2 = bf2f(us.y & 0xffffu) * w0;
    float a3 = bf2f(us.y >> 16) * w0;
    int e  = off[node];
    int e1 = off[node + 1];
    for (; e + 4 <= e1; e += 4) {
        int2 p0 = pair[e + 0];
        int2 p1 = pair[e + 1];
        int2 p2 = pair[e + 2];
        int2 p3 = pair[e + 3];
        uint2 u0 = *(const uint2*)(hb + ((size_t)p0.x << 7) + lane * 4);
        uint2 u1 = *(const uint2*)(hb + ((size_t)p1.x << 7) + lane * 4);
        uint2 u2 = *(const uint2*)(hb + ((size_t)p2.x << 7) + lane * 4);
        uint2 u3 = *(const uint2*)(hb + ((size_t)p3.x << 7) + lane * 4);
        float w0e = __int_as_float(p0.y);
        float w1e = __int_as_float(p1.y);
        float w2e = __int_as_float(p2.y);
        float w3e = __int_as_float(p3.y);
        a0 += w0e * bf2f(u0.x & 0xffffu); a1 += w0e * bf2f(u0.x >> 16);
        a2 += w0e * bf2f(u0.y & 0xffffu); a3 += w0e * bf2f(u0.y >> 16);
        a0 += w1e * bf2f(u1.x & 0xffffu); a1 += w1e * bf2f(u1.x >> 16);
        a2 += w1e * bf2f(u1.y & 0xffffu); a3 += w1e * bf2f(u1.y >> 16);
        a0 += w2e * bf2f(u2.x & 0xffffu); a1 += w2e * bf2f(u2.x >> 16);
        a2 += w2e * bf2f(u2.y & 0xffffu); a3 += w2e * bf2f(u2.y >> 16);
        a0 += w3e * bf2f(u3.x & 0xffffu); a1 += w3e * bf2f(u3.x >> 16);
        a2 += w3e * bf2f(u3.y & 0xffffu); a3 += w3e * bf2f(u3.y >> 16);
    }
    for (; e < e1; ++e) {
        int2 p = pair[e];
        float w = __int_as_float(p.y);
        uint2 u = *(const uint2*)(hb + ((size_t)p.x << 7) + lane * 4);
        a0 += w * bf2f(u.x & 0xffffu); a1 += w * bf2f(u.x >> 16);
        a2 += w * bf2f(u.y & 0xffffu); a3 += w * bf2f(u.y >> 16);
    }
    float4 b = *(const float4*)&bias[lane * 4];
    a0 += b.x; a1 += b.y; a2 += b.z; a3 += b.w;
    if (RELU) {
        a0 = fmaxf(a0, 0.f); a1 = fmaxf(a1, 0.f);
        a2 = fmaxf(a2, 0.f); a3 = fmaxf(a3, 0.f);
    }
    *(float4*)(out + ((size_t)node << 7) + lane * 4) = make_float4(a0, a1, a2, a3);
}

extern "C" void kernel_launch(void* const* d_in, const int* in_sizes, int n_in,
                              void* d_out, int out_size, void* d_ws, size_t ws_size,
                              hipStream_t stream) {
    const float* x  = (const float*)d_in[0];
    const float* W1 = (const float*)d_in[1];
    const float* b1 = (const float*)d_in[2];
    const float* W2 = (const float*)d_in[3];
    const float* b2 = (const float*)d_in[4];
    const int*   ei = (const int*)d_in[5];

    const int n = NN;
    const int E = in_sizes[5] / 2;
    const int* row = ei;        // sources
    const int* col = ei + E;    // targets

    char* ws = (char*)d_ws;
    size_t o = 0;
    auto alloc = [&](size_t bytes) {
        void* p = ws + o;
        o = (o + bytes + 255) & ~(size_t)255;
        return p;
    };
    int*            cnt   = (int*)alloc((size_t)n * 4);
    int*            offs  = (int*)alloc((size_t)(n + 1) * 4);
    int*            bsum  = (int*)alloc(512 * 4);
    float*          dinv  = (float*)alloc((size_t)n * 4);
    int2*           pair  = (int2*)alloc((size_t)E * 8);
    unsigned short* bufH  = (unsigned short*)alloc((size_t)n * NH * 2);  // bf16 h
    float*          bufG  = (float*)alloc((size_t)n * NH * 4);           // f32 g
    unsigned short* wt1hi = (unsigned short*)alloc(256 * 128 * 2);
    unsigned short* wt1lo = (unsigned short*)alloc(256 * 128 * 2);
    unsigned short* wt2hi = (unsigned short*)alloc(128 * 128 * 2);
    unsigned short* wt2lo = (unsigned short*)alloc(128 * 128 * 2);

    int nb = (n + 255) / 256;  // 391

    // W prepasses (independent of CSR build)
    k_wprep<<<(256 * 128 + 255) / 256, 256, 0, stream>>>(W1, wt1hi, wt1lo, 256);
    k_wprep<<<(128 * 128 + 255) / 256, 256, 0, stream>>>(W2, wt2hi, wt2lo, 128);

    hipMemsetAsync(cnt, 0, (size_t)n * 4, stream);
    k_count<<<(E + 255) / 256, 256, 0, stream>>>(col, cnt, E);
    k_dinv<<<nb, 256, 0, stream>>>(cnt, dinv, n);
    k_scan_block<<<nb, 256, 0, stream>>>(cnt, offs, bsum, n);
    k_scan_sums<<<1, 512, 0, stream>>>(bsum, nb);
    k_scan_add<<<nb, 256, 0, stream>>>(offs, bsum, cnt, n);
    hipMemsetAsync(cnt, 0, (size_t)n * 4, stream);  // reuse as cursor
    k_fill<<<(E + 255) / 256, 256, 0, stream>>>(row, col, offs, cnt, dinv, pair, E);

    int aggBlocks = (n + 7) / 8;
    int gemmBlocks = (n + 127) / 128;
    // layer 1: h = x@W1 (bf16) ; g = relu(agg(h) + b1) (f32)
    k_gemm_mfma<256><<<gemmBlocks, 256, 0, stream>>>(x, wt1hi, wt1lo, bufH, n);
    k_agg<true><<<aggBlocks, 256, 0, stream>>>(bufH, dinv, offs, pair, b1, bufG, n);
    // layer 2: h = g@W2 (bf16) ; out = agg(h) + b2 (f32)
    k_gemm_mfma<128><<<gemmBlocks, 256, 0, stream>>>(bufG, wt2hi, wt2lo, bufH, n);
    k_agg<false><<<aggBlocks, 256, 0, stream>>>(bufH, dinv, offs, pair, b2, (float*)d_out, n);
}

// Round 5
// 415.871 us; speedup vs baseline: 1.4956x; 1.0150x over previous
//
#include <hip/hip_runtime.h>

// GCN encoder: 2x GCNConv (PyG semantics: self-loops, symmetric norm, aggregate at col)
// x:[100000,256] f32, W1:[256,128], b1:[128], W2:[128,128], b2:[128], edge_index:[2,1600000] int
// out:[100000,128] f32
//
// Pipeline: CSR-by-target build -> MFMA GEMM1 (hi/lo bf16 split, near-f32 accurate, bf16 out)
//           -> agg1(bf16 gather, +b1, relu) -> MFMA GEMM2 -> agg2 -> out f32.
// GEMM: wave = 32 rows x 64 cols, explicit B-frag register arrays + A prefetch for MLP.

#define NN 100000
#define NH 128

__device__ __forceinline__ float bf2f(unsigned int u) { return __uint_as_float(u << 16); }
__device__ __forceinline__ unsigned short f2bf(float f) {
    unsigned int u = __float_as_uint(f);
    u = (u + 0x7fffu + ((u >> 16) & 1u)) >> 16;   // RNE
    return (unsigned short)u;
}

// ---------------- CSR build ----------------
__global__ void k_count(const int* __restrict__ col, int* __restrict__ cnt, int E) {
    int e = blockIdx.x * 256 + threadIdx.x;
    if (e < E) atomicAdd(&cnt[col[e]], 1);
}

__global__ void k_dinv(const int* __restrict__ cnt, float* __restrict__ dinv, int n) {
    int i = blockIdx.x * 256 + threadIdx.x;
    if (i < n) dinv[i] = rsqrtf(1.0f + (float)cnt[i]);   // deg = 1 (self-loop) + in-degree
}

__global__ void k_scan_block(const int* __restrict__ in, int* __restrict__ out,
                             int* __restrict__ bsum, int n) {
    __shared__ int s[256];
    int i = blockIdx.x * 256 + threadIdx.x;
    int v = (i < n) ? in[i] : 0;
    s[threadIdx.x] = v;
    __syncthreads();
    for (int off = 1; off < 256; off <<= 1) {
        int t = (threadIdx.x >= off) ? s[threadIdx.x - off] : 0;
        __syncthreads();
        s[threadIdx.x] += t;
        __syncthreads();
    }
    if (i < n) out[i] = s[threadIdx.x] - v;             // exclusive within block
    if (threadIdx.x == 255) bsum[blockIdx.x] = s[255];  // block total
}

__global__ void k_scan_sums(int* bsum, int nb) {  // nb <= 512, single block of 512
    __shared__ int s[512];
    int tid = threadIdx.x;
    int v = (tid < nb) ? bsum[tid] : 0;
    s[tid] = v;
    __syncthreads();
    for (int off = 1; off < 512; off <<= 1) {
        int t = (tid >= off) ? s[tid - off] : 0;
        __syncthreads();
        s[tid] += t;
        __syncthreads();
    }
    if (tid < nb) bsum[tid] = s[tid] - v;               // exclusive block offsets
}

__global__ void k_scan_add(int* __restrict__ off, const int* __restrict__ bsum,
                           const int* __restrict__ cnt, int n) {
    int i = blockIdx.x * 256 + threadIdx.x;
    if (i < n) {
        int o = off[i] + bsum[blockIdx.x];
        off[i] = o;
        if (i == n - 1) off[n] = o + cnt[i];
    }
}

// fill CSR with packed (src, weight) per edge; cur is a zeroed cursor array
__global__ void k_fill(const int* __restrict__ row, const int* __restrict__ col,
                       const int* __restrict__ off, int* __restrict__ cur,
                       const float* __restrict__ dinv, int2* __restrict__ pair, int E) {
    int e = blockIdx.x * 256 + threadIdx.x;
    if (e < E) {
        int c = col[e];
        int s = row[e];
        int slot = off[c] + atomicAdd(&cur[c], 1);
        pair[slot] = make_int2(s, __float_as_int(dinv[s] * dinv[c]));
    }
}

// ---------------- W prepass: f32 [K][128] -> transposed bf16 hi/lo [128][K] ----------------
__global__ void k_wprep(const float* __restrict__ W, unsigned short* __restrict__ Thi,
                        unsigned short* __restrict__ Tlo, int K) {
    int idx = blockIdx.x * 256 + threadIdx.x;
    if (idx >= K * 128) return;
    int k = idx >> 7, c = idx & 127;
    float w = W[idx];
    unsigned int u = __float_as_uint(w) & 0xffff0000u;   // truncate hi
    float rem = w - __uint_as_float(u);
    Thi[(size_t)c * K + k] = (unsigned short)(u >> 16);
    Tlo[(size_t)c * K + k] = (unsigned short)(__float_as_uint(rem) >> 16);
}

// ---------------- MFMA GEMM: C[M,128](bf16) = A[M,K](f32) @ W[K,128] ----------------
// Split A and W into bf16 hi+lo; AhBh + AlBh + AhBl ~= f32-accurate.
// Wave = 32 rows x 64 cols (grid.y selects col half). Per K-step: batch-load 8 B-frags
// into register arrays (independent 16B loads), prefetch next A, then 24 MFMAs.
template <int K>
__global__ __launch_bounds__(256) void k_gemm_mfma(const float* __restrict__ A,
                                                   const unsigned short* __restrict__ Bhi,
                                                   const unsigned short* __restrict__ Blo,
                                                   unsigned short* __restrict__ C, int M) {
    using bf16x8 = __attribute__((ext_vector_type(8))) short;
    using f32x4  = __attribute__((ext_vector_type(4))) float;
    const int lane  = threadIdx.x & 63;
    const int wv    = threadIdx.x >> 6;       // 0..3
    const int r     = lane & 15;              // A-row / B-col within frag
    const int kb    = lane >> 4;              // k-block 0..3
    const int wrow  = blockIdx.x * 128 + wv * 32;
    const int cbase = blockIdx.y * 64;        // column half

    int row0 = wrow + r;       if (row0 >= M) row0 = M - 1;
    int row1 = wrow + 16 + r;  if (row1 >= M) row1 = M - 1;
    const float* a0p = A + (size_t)row0 * K + kb * 8;
    const float* a1p = A + (size_t)row1 * K + kb * 8;

    f32x4 acc[2][4];
#pragma unroll
    for (int m = 0; m < 2; ++m)
#pragma unroll
        for (int t = 0; t < 4; ++t) acc[m][t] = (f32x4){0.f, 0.f, 0.f, 0.f};

    float4 a_cur[4];
    a_cur[0] = *(const float4*)(a0p);
    a_cur[1] = *(const float4*)(a0p + 4);
    a_cur[2] = *(const float4*)(a1p);
    a_cur[3] = *(const float4*)(a1p + 4);

#pragma unroll
    for (int ks = 0; ks < K / 32; ++ks) {
        const int kk = ks * 32;
        // batch-load all B frags for this K-step (8 independent 16B loads)
        bf16x8 bh[4], bl[4];
#pragma unroll
        for (int t = 0; t < 4; ++t) {
            const size_t bo = (size_t)(cbase + t * 16 + r) * K + kk + kb * 8;
            bh[t] = *(const bf16x8*)(Bhi + bo);
            bl[t] = *(const bf16x8*)(Blo + bo);
        }
        // prefetch next A
        float4 a_nxt[4];
#pragma unroll
        for (int i = 0; i < 4; ++i) a_nxt[i] = a_cur[i];
        if (ks + 1 < K / 32) {
            a_nxt[0] = *(const float4*)(a0p + kk + 32);
            a_nxt[1] = *(const float4*)(a0p + kk + 36);
            a_nxt[2] = *(const float4*)(a1p + kk + 32);
            a_nxt[3] = *(const float4*)(a1p + kk + 36);
        }
        // convert current A -> hi/lo bf16 frags
        bf16x8 ah[2], al[2];
        const float* af = (const float*)a_cur;
#pragma unroll
        for (int m = 0; m < 2; ++m) {
#pragma unroll
            for (int j = 0; j < 8; ++j) {
                float v = af[m * 8 + j];
                unsigned int u = __float_as_uint(v) & 0xffff0000u;
                ah[m][j] = (short)(u >> 16);
                al[m][j] = (short)(__float_as_uint(v - __uint_as_float(u)) >> 16);
            }
        }
#pragma unroll
        for (int t = 0; t < 4; ++t) {
#pragma unroll
            for (int m = 0; m < 2; ++m) {
                acc[m][t] = __builtin_amdgcn_mfma_f32_16x16x32_bf16(ah[m], bh[t], acc[m][t], 0, 0, 0);
                acc[m][t] = __builtin_amdgcn_mfma_f32_16x16x32_bf16(al[m], bh[t], acc[m][t], 0, 0, 0);
                acc[m][t] = __builtin_amdgcn_mfma_f32_16x16x32_bf16(ah[m], bl[t], acc[m][t], 0, 0, 0);
            }
        }
#pragma unroll
        for (int i = 0; i < 4; ++i) a_cur[i] = a_nxt[i];
    }
    // C/D layout (m89-verified): col = lane&15, row = (lane>>4)*4 + reg
#pragma unroll
    for (int m = 0; m < 2; ++m) {
        int ob = wrow + m * 16 + kb * 4;
#pragma unroll
        for (int t = 0; t < 4; ++t) {
#pragma unroll
            for (int q = 0; q < 4; ++q) {
                int orow = ob + q;
                if (orow < M) C[(size_t)orow * 128 + cbase + t * 16 + r] = f2bf(acc[m][t][q]);
            }
        }
    }
}

// ---------------- aggregate ----------------
// out[i] = sum_{e: col=i} h[src_e]*w_e + h[i]*dinv[i]^2 + b
// 32 lanes per node (4 feats/lane, uint2=8B), 2 nodes per wave, edge loop unrolled 4x
// so ~8 independent row gathers are in flight per wave.
template <bool RELU>
__global__ __launch_bounds__(256) void k_agg(const unsigned short* __restrict__ hb,
                                             const float* __restrict__ dinv,
                                             const int* __restrict__ off,
                                             const int2* __restrict__ pair,
                                             const float* __restrict__ bias,
                                             float* __restrict__ out, int n) {
    int node = blockIdx.x * 8 + (threadIdx.x >> 5);
    int lane = threadIdx.x & 31;
    if (node >= n) return;
    float di = dinv[node];
    uint2 us = *(const uint2*)(hb + ((size_t)node << 7) + lane * 4);
    float w0 = di * di;
    float a0 = bf2f(us.x & 0xffffu) * w0;
    float a1 = bf2f(us.x >> 16) * w0;
    float a2 = bf2f(us.y & 0xffffu) * w0;
    float a3 = bf2f(us.y >> 16) * w0;
    int e  = off[node];
    int e1 = off[node + 1];
    for (; e + 4 <= e1; e += 4) {
        int2 p0 = pair[e + 0];
        int2 p1 = pair[e + 1];
        int2 p2 = pair[e + 2];
        int2 p3 = pair[e + 3];
        uint2 u0 = *(const uint2*)(hb + ((size_t)p0.x << 7) + lane * 4);
        uint2 u1 = *(const uint2*)(hb + ((size_t)p1.x << 7) + lane * 4);
        uint2 u2 = *(const uint2*)(hb + ((size_t)p2.x << 7) + lane * 4);
        uint2 u3 = *(const uint2*)(hb + ((size_t)p3.x << 7) + lane * 4);
        float w0e = __int_as_float(p0.y);
        float w1e = __int_as_float(p1.y);
        float w2e = __int_as_float(p2.y);
        float w3e = __int_as_float(p3.y);
        a0 += w0e * bf2f(u0.x & 0xffffu); a1 += w0e * bf2f(u0.x >> 16);
        a2 += w0e * bf2f(u0.y & 0xffffu); a3 += w0e * bf2f(u0.y >> 16);
        a0 += w1e * bf2f(u1.x & 0xffffu); a1 += w1e * bf2f(u1.x >> 16);
        a2 += w1e * bf2f(u1.y & 0xffffu); a3 += w1e * bf2f(u1.y >> 16);
        a0 += w2e * bf2f(u2.x & 0xffffu); a1 += w2e * bf2f(u2.x >> 16);
        a2 += w2e * bf2f(u2.y & 0xffffu); a3 += w2e * bf2f(u2.y >> 16);
        a0 += w3e * bf2f(u3.x & 0xffffu); a1 += w3e * bf2f(u3.x >> 16);
        a2 += w3e * bf2f(u3.y & 0xffffu); a3 += w3e * bf2f(u3.y >> 16);
    }
    for (; e < e1; ++e) {
        int2 p = pair[e];
        float w = __int_as_float(p.y);
        uint2 u = *(const uint2*)(hb + ((size_t)p.x << 7) + lane * 4);
        a0 += w * bf2f(u.x & 0xffffu); a1 += w * bf2f(u.x >> 16);
        a2 += w * bf2f(u.y & 0xffffu); a3 += w * bf2f(u.y >> 16);
    }
    float4 b = *(const float4*)&bias[lane * 4];
    a0 += b.x; a1 += b.y; a2 += b.z; a3 += b.w;
    if (RELU) {
        a0 = fmaxf(a0, 0.f); a1 = fmaxf(a1, 0.f);
        a2 = fmaxf(a2, 0.f); a3 = fmaxf(a3, 0.f);
    }
    *(float4*)(out + ((size_t)node << 7) + lane * 4) = make_float4(a0, a1, a2, a3);
}

extern "C" void kernel_launch(void* const* d_in, const int* in_sizes, int n_in,
                              void* d_out, int out_size, void* d_ws, size_t ws_size,
                              hipStream_t stream) {
    const float* x  = (const float*)d_in[0];
    const float* W1 = (const float*)d_in[1];
    const float* b1 = (const float*)d_in[2];
    const float* W2 = (const float*)d_in[3];
    const float* b2 = (const float*)d_in[4];
    const int*   ei = (const int*)d_in[5];

    const int n = NN;
    const int E = in_sizes[5] / 2;
    const int* row = ei;        // sources
    const int* col = ei + E;    // targets

    char* ws = (char*)d_ws;
    size_t o = 0;
    auto alloc = [&](size_t bytes) {
        void* p = ws + o;
        o = (o + bytes + 255) & ~(size_t)255;
        return p;
    };
    int*            cnt   = (int*)alloc((size_t)n * 4);
    int*            offs  = (int*)alloc((size_t)(n + 1) * 4);
    int*            bsum  = (int*)alloc(512 * 4);
    float*          dinv  = (float*)alloc((size_t)n * 4);
    int2*           pair  = (int2*)alloc((size_t)E * 8);
    unsigned short* bufH  = (unsigned short*)alloc((size_t)n * NH * 2);  // bf16 h
    float*          bufG  = (float*)alloc((size_t)n * NH * 4);           // f32 g
    unsigned short* wt1hi = (unsigned short*)alloc(256 * 128 * 2);
    unsigned short* wt1lo = (unsigned short*)alloc(256 * 128 * 2);
    unsigned short* wt2hi = (unsigned short*)alloc(128 * 128 * 2);
    unsigned short* wt2lo = (unsigned short*)alloc(128 * 128 * 2);

    int nb = (n + 255) / 256;  // 391

    // W prepasses (independent of CSR build)
    k_wprep<<<(256 * 128 + 255) / 256, 256, 0, stream>>>(W1, wt1hi, wt1lo, 256);
    k_wprep<<<(128 * 128 + 255) / 256, 256, 0, stream>>>(W2, wt2hi, wt2lo, 128);

    hipMemsetAsync(cnt, 0, (size_t)n * 4, stream);
    k_count<<<(E + 255) / 256, 256, 0, stream>>>(col, cnt, E);
    k_dinv<<<nb, 256, 0, stream>>>(cnt, dinv, n);
    k_scan_block<<<nb, 256, 0, stream>>>(cnt, offs, bsum, n);
    k_scan_sums<<<1, 512, 0, stream>>>(bsum, nb);
    k_scan_add<<<nb, 256, 0, stream>>>(offs, bsum, cnt, n);
    hipMemsetAsync(cnt, 0, (size_t)n * 4, stream);  // reuse as cursor
    k_fill<<<(E + 255) / 256, 256, 0, stream>>>(row, col, offs, cnt, dinv, pair, E);

    int aggBlocks = (n + 7) / 8;
    dim3 gemmGrid((n + 127) / 128, 2);
    // layer 1: h = x@W1 (bf16) ; g = relu(agg(h) + b1) (f32)
    k_gemm_mfma<256><<<gemmGrid, 256, 0, stream>>>(x, wt1hi, wt1lo, bufH, n);
    k_agg<true><<<aggBlocks, 256, 0, stream>>>(bufH, dinv, offs, pair, b1, bufG, n);
    // layer 2: h = g@W2 (bf16) ; out = agg(h) + b2 (f32)
    k_gemm_mfma<128><<<gemmGrid, 256, 0, stream>>>(bufG, wt2hi, wt2lo, bufH, n);
    k_agg<false><<<aggBlocks, 256, 0, stream>>>(bufH, dinv, offs, pair, b2, (float*)d_out, n);
}

// Round 6
// 370.425 us; speedup vs baseline: 1.6791x; 1.1227x over previous
//
#include <hip/hip_runtime.h>

// GCN encoder: 2x GCNConv (PyG semantics: self-loops, symmetric norm, aggregate at col)
// x:[100000,256] f32, W1:[256,128], b1:[128], W2:[128,128], b2:[128], edge_index:[2,1600000] int
// out:[100000,128] f32
//
// Pipeline: CSR-by-target build -> MFMA GEMM1 (hi/lo bf16 split, near-f32 accurate, bf16 out)
//           -> agg1(bf16 gather, +b1, relu) -> MFMA GEMM2 -> agg2 -> out f32.
// GEMM: global_load_lds double-buffered staging (m97 pattern), 128x128 tile, BK=32.

#define NN 100000
#define NH 128

__device__ __forceinline__ float bf2f(unsigned int u) { return __uint_as_float(u << 16); }
__device__ __forceinline__ unsigned short f2bf(float f) {
    unsigned int u = __float_as_uint(f);
    u = (u + 0x7fffu + ((u >> 16) & 1u)) >> 16;   // RNE
    return (unsigned short)u;
}

// async 16B/lane global->LDS DMA; lds dest = wave-uniform base + lane*16
__device__ __forceinline__ void dma16(const void* g, void* l) {
    __builtin_amdgcn_global_load_lds(
        (const __attribute__((address_space(1))) unsigned int*)g,
        (__attribute__((address_space(3))) unsigned int*)l, 16, 0, 0);
}

// ---------------- CSR build ----------------
__global__ void k_count(const int* __restrict__ col, int* __restrict__ cnt, int E) {
    int e = blockIdx.x * 256 + threadIdx.x;
    if (e < E) atomicAdd(&cnt[col[e]], 1);
}

__global__ void k_dinv(const int* __restrict__ cnt, float* __restrict__ dinv, int n) {
    int i = blockIdx.x * 256 + threadIdx.x;
    if (i < n) dinv[i] = rsqrtf(1.0f + (float)cnt[i]);   // deg = 1 (self-loop) + in-degree
}

__global__ void k_scan_block(const int* __restrict__ in, int* __restrict__ out,
                             int* __restrict__ bsum, int n) {
    __shared__ int s[256];
    int i = blockIdx.x * 256 + threadIdx.x;
    int v = (i < n) ? in[i] : 0;
    s[threadIdx.x] = v;
    __syncthreads();
    for (int off = 1; off < 256; off <<= 1) {
        int t = (threadIdx.x >= off) ? s[threadIdx.x - off] : 0;
        __syncthreads();
        s[threadIdx.x] += t;
        __syncthreads();
    }
    if (i < n) out[i] = s[threadIdx.x] - v;             // exclusive within block
    if (threadIdx.x == 255) bsum[blockIdx.x] = s[255];  // block total
}

__global__ void k_scan_sums(int* bsum, int nb) {  // nb <= 512, single block of 512
    __shared__ int s[512];
    int tid = threadIdx.x;
    int v = (tid < nb) ? bsum[tid] : 0;
    s[tid] = v;
    __syncthreads();
    for (int off = 1; off < 512; off <<= 1) {
        int t = (tid >= off) ? s[tid - off] : 0;
        __syncthreads();
        s[tid] += t;
        __syncthreads();
    }
    if (tid < nb) bsum[tid] = s[tid] - v;               // exclusive block offsets
}

__global__ void k_scan_add(int* __restrict__ off, const int* __restrict__ bsum,
                           const int* __restrict__ cnt, int n) {
    int i = blockIdx.x * 256 + threadIdx.x;
    if (i < n) {
        int o = off[i] + bsum[blockIdx.x];
        off[i] = o;
        if (i == n - 1) off[n] = o + cnt[i];
    }
}

// fill CSR with packed (src, weight) per edge; cur is a zeroed cursor array
__global__ void k_fill(const int* __restrict__ row, const int* __restrict__ col,
                       const int* __restrict__ off, int* __restrict__ cur,
                       const float* __restrict__ dinv, int2* __restrict__ pair, int E) {
    int e = blockIdx.x * 256 + threadIdx.x;
    if (e < E) {
        int c = col[e];
        int s = row[e];
        int slot = off[c] + atomicAdd(&cur[c], 1);
        pair[slot] = make_int2(s, __float_as_int(dinv[s] * dinv[c]));
    }
}

// ---------------- W prepass: f32 [K][128] -> transposed bf16 hi/lo [128][K] ----------------
__global__ void k_wprep(const float* __restrict__ W, unsigned short* __restrict__ Thi,
                        unsigned short* __restrict__ Tlo, int K) {
    int idx = blockIdx.x * 256 + threadIdx.x;
    if (idx >= K * 128) return;
    int k = idx >> 7, c = idx & 127;
    float w = W[idx];
    unsigned int u = __float_as_uint(w) & 0xffff0000u;   // truncate hi
    float rem = w - __uint_as_float(u);
    Thi[(size_t)c * K + k] = (unsigned short)(u >> 16);
    Tlo[(size_t)c * K + k] = (unsigned short)(__float_as_uint(rem) >> 16);
}

// ---------------- MFMA GEMM: C[M,128](bf16) = A[M,K](f32) @ W[K,128] ----------------
// hi/lo bf16 split: AhBh + AlBh + AhBl ~= f32-accurate.
// Block = 128 rows x 128 cols, 4 waves (32 rows each), BK=32, double-buffered LDS
// filled via global_load_lds DMA. One __syncthreads per K-step (compiler emits the
// vmcnt(0)+lgkmcnt(0) drain); buf[ks&1] double-buffer makes the single barrier race-free.
// LDS layouts (16B slots): A[kb][j][row] so frag reads are consecutive-slot (conflict-free);
// B[kb][col] likewise. DMA dest is linear; per-lane SOURCE addresses realize the layout.
template <int K>
__global__ __launch_bounds__(256) void k_gemm_mfma(const float* __restrict__ A,
                                                   const unsigned short* __restrict__ Bhi,
                                                   const unsigned short* __restrict__ Blo,
                                                   unsigned short* __restrict__ C, int M) {
    using bf16x8 = __attribute__((ext_vector_type(8))) short;
    using f32x4  = __attribute__((ext_vector_type(4))) float;
    constexpr int T = K / 32;
    __shared__ uint4 sA4[2][1024];     // [buf][kb*256 + j*128 + row]  (f32 A, 16KB/buf)
    __shared__ uint4 sB4[2][2][512];   // [buf][hi/lo][kb*128 + col]   (bf16 B, 8KB each)

    const int lane = threadIdx.x & 63;
    const int wv   = threadIdx.x >> 6;       // 0..3
    const int r    = lane & 15;              // row/col within frag
    const int kb   = lane >> 4;              // k-block 0..3
    const int rowBase = blockIdx.x * 128;

    f32x4 acc[2][8];
#pragma unroll
    for (int m = 0; m < 2; ++m)
#pragma unroll
        for (int t = 0; t < 8; ++t) acc[m][t] = (f32x4){0.f, 0.f, 0.f, 0.f};

#pragma unroll
    for (int ks = 0; ks < T; ++ks) {
        const int buf = ks & 1;
        const int kk  = ks * 32;
        // ---- stage A tile: 1024 slots, 4 chunks/wave ----
#pragma unroll
        for (int c = 0; c < 4; ++c) {
            int sb = wv * 256 + c * 64;            // wave-uniform slot base
            int s  = sb + lane;
            int akb = s >> 8, aj = (s >> 7) & 1, ar = s & 127;
            int gr = rowBase + ar; if (gr >= M) gr = M - 1;
            dma16(A + (size_t)gr * K + kk + akb * 8 + aj * 4, &sA4[buf][sb]);
        }
        // ---- stage B hi/lo: 512 slots each, 2 chunks/wave ----
#pragma unroll
        for (int hl = 0; hl < 2; ++hl) {
            const unsigned short* Bp = hl ? Blo : Bhi;
#pragma unroll
            for (int c = 0; c < 2; ++c) {
                int sb = wv * 128 + c * 64;
                int s  = sb + lane;
                int bkb = s >> 7, bcol = s & 127;
                dma16(Bp + (size_t)bcol * K + kk + bkb * 8, &sB4[buf][hl][sb]);
            }
        }
        __syncthreads();   // full vmcnt/lgkmcnt drain: tile ready, prev reads done
        // ---- A frags: convert f32 -> bf16 hi/lo ----
        bf16x8 ah[2], al[2];
#pragma unroll
        for (int m = 0; m < 2; ++m) {
            int rowl = wv * 32 + m * 16 + r;
            uint4 u0 = sA4[buf][kb * 256 + rowl];          // k = kb*8 + 0..3
            uint4 u1 = sA4[buf][kb * 256 + 128 + rowl];    // k = kb*8 + 4..7
            float f[8];
            *(uint4*)&f[0] = u0;
            *(uint4*)&f[4] = u1;
#pragma unroll
            for (int j = 0; j < 8; ++j) {
                float v = f[j];
                unsigned int u = __float_as_uint(v) & 0xffff0000u;
                ah[m][j] = (short)(u >> 16);
                al[m][j] = (short)(__float_as_uint(v - __uint_as_float(u)) >> 16);
            }
        }
        // ---- B frags + MFMAs ----
#pragma unroll
        for (int t = 0; t < 8; ++t) {
            int col = t * 16 + r;
            bf16x8 bh = *(const bf16x8*)&sB4[buf][0][kb * 128 + col];
            bf16x8 bl = *(const bf16x8*)&sB4[buf][1][kb * 128 + col];
#pragma unroll
            for (int m = 0; m < 2; ++m) {
                acc[m][t] = __builtin_amdgcn_mfma_f32_16x16x32_bf16(ah[m], bh, acc[m][t], 0, 0, 0);
                acc[m][t] = __builtin_amdgcn_mfma_f32_16x16x32_bf16(al[m], bh, acc[m][t], 0, 0, 0);
                acc[m][t] = __builtin_amdgcn_mfma_f32_16x16x32_bf16(ah[m], bl, acc[m][t], 0, 0, 0);
            }
        }
    }
    // C/D layout (m89-verified): col = lane&15, row = (lane>>4)*4 + reg
    const int wrow = rowBase + wv * 32;
#pragma unroll
    for (int m = 0; m < 2; ++m) {
        int ob = wrow + m * 16 + kb * 4;
#pragma unroll
        for (int t = 0; t < 8; ++t) {
#pragma unroll
            for (int q = 0; q < 4; ++q) {
                int orow = ob + q;
                if (orow < M) C[(size_t)orow * 128 + t * 16 + r] = f2bf(acc[m][t][q]);
            }
        }
    }
}

// ---------------- aggregate ----------------
// out[i] = sum_{e: col=i} h[src_e]*w_e + h[i]*dinv[i]^2 + b
// 32 lanes per node (4 feats/lane, uint2=8B), 2 nodes per wave, edge loop unrolled 4x
// so ~8 independent row gathers are in flight per wave.
template <bool RELU>
__global__ __launch_bounds__(256) void k_agg(const unsigned short* __restrict__ hb,
                                             const float* __restrict__ dinv,
                                             const int* __restrict__ off,
                                             const int2* __restrict__ pair,
                                             const float* __restrict__ bias,
                                             float* __restrict__ out, int n) {
    int node = blockIdx.x * 8 + (threadIdx.x >> 5);
    int lane = threadIdx.x & 31;
    if (node >= n) return;
    float di = dinv[node];
    uint2 us = *(const uint2*)(hb + ((size_t)node << 7) + lane * 4);
    float w0 = di * di;
    float a0 = bf2f(us.x & 0xffffu) * w0;
    float a1 = bf2f(us.x >> 16) * w0;
    float a2 = bf2f(us.y & 0xffffu) * w0;
    float a3 = bf2f(us.y >> 16) * w0;
    int e  = off[node];
    int e1 = off[node + 1];
    for (; e + 4 <= e1; e += 4) {
        int2 p0 = pair[e + 0];
        int2 p1 = pair[e + 1];
        int2 p2 = pair[e + 2];
        int2 p3 = pair[e + 3];
        uint2 u0 = *(const uint2*)(hb + ((size_t)p0.x << 7) + lane * 4);
        uint2 u1 = *(const uint2*)(hb + ((size_t)p1.x << 7) + lane * 4);
        uint2 u2 = *(const uint2*)(hb + ((size_t)p2.x << 7) + lane * 4);
        uint2 u3 = *(const uint2*)(hb + ((size_t)p3.x << 7) + lane * 4);
        float w0e = __int_as_float(p0.y);
        float w1e = __int_as_float(p1.y);
        float w2e = __int_as_float(p2.y);
        float w3e = __int_as_float(p3.y);
        a0 += w0e * bf2f(u0.x & 0xffffu); a1 += w0e * bf2f(u0.x >> 16);
        a2 += w0e * bf2f(u0.y & 0xffffu); a3 += w0e * bf2f(u0.y >> 16);
        a0 += w1e * bf2f(u1.x & 0xffffu); a1 += w1e * bf2f(u1.x >> 16);
        a2 += w1e * bf2f(u1.y & 0xffffu); a3 += w1e * bf2f(u1.y >> 16);
        a0 += w2e * bf2f(u2.x & 0xffffu); a1 += w2e * bf2f(u2.x >> 16);
        a2 += w2e * bf2f(u2.y & 0xffffu); a3 += w2e * bf2f(u2.y >> 16);
        a0 += w3e * bf2f(u3.x & 0xffffu); a1 += w3e * bf2f(u3.x >> 16);
        a2 += w3e * bf2f(u3.y & 0xffffu); a3 += w3e * bf2f(u3.y >> 16);
    }
    for (; e < e1; ++e) {
        int2 p = pair[e];
        float w = __int_as_float(p.y);
        uint2 u = *(const uint2*)(hb + ((size_t)p.x << 7) + lane * 4);
        a0 += w * bf2f(u.x & 0xffffu); a1 += w * bf2f(u.x >> 16);
        a2 += w * bf2f(u.y & 0xffffu); a3 += w * bf2f(u.y >> 16);
    }
    float4 b = *(const float4*)&bias[lane * 4];
    a0 += b.x; a1 += b.y; a2 += b.z; a3 += b.w;
    if (RELU) {
        a0 = fmaxf(a0, 0.f); a1 = fmaxf(a1, 0.f);
        a2 = fmaxf(a2, 0.f); a3 = fmaxf(a3, 0.f);
    }
    *(float4*)(out + ((size_t)node << 7) + lane * 4) = make_float4(a0, a1, a2, a3);
}

extern "C" void kernel_launch(void* const* d_in, const int* in_sizes, int n_in,
                              void* d_out, int out_size, void* d_ws, size_t ws_size,
                              hipStream_t stream) {
    const float* x  = (const float*)d_in[0];
    const float* W1 = (const float*)d_in[1];
    const float* b1 = (const float*)d_in[2];
    const float* W2 = (const float*)d_in[3];
    const float* b2 = (const float*)d_in[4];
    const int*   ei = (const int*)d_in[5];

    const int n = NN;
    const int E = in_sizes[5] / 2;
    const int* row = ei;        // sources
    const int* col = ei + E;    // targets

    char* ws = (char*)d_ws;
    size_t o = 0;
    auto alloc = [&](size_t bytes) {
        void* p = ws + o;
        o = (o + bytes + 255) & ~(size_t)255;
        return p;
    };
    int*            cnt   = (int*)alloc((size_t)n * 4);
    int*            offs  = (int*)alloc((size_t)(n + 1) * 4);
    int*            bsum  = (int*)alloc(512 * 4);
    float*          dinv  = (float*)alloc((size_t)n * 4);
    int2*           pair  = (int2*)alloc((size_t)E * 8);
    unsigned short* bufH  = (unsigned short*)alloc((size_t)n * NH * 2);  // bf16 h
    float*          bufG  = (float*)alloc((size_t)n * NH * 4);           // f32 g
    unsigned short* wt1hi = (unsigned short*)alloc(256 * 128 * 2);
    unsigned short* wt1lo = (unsigned short*)alloc(256 * 128 * 2);
    unsigned short* wt2hi = (unsigned short*)alloc(128 * 128 * 2);
    unsigned short* wt2lo = (unsigned short*)alloc(128 * 128 * 2);

    int nb = (n + 255) / 256;  // 391

    // W prepasses (independent of CSR build)
    k_wprep<<<(256 * 128 + 255) / 256, 256, 0, stream>>>(W1, wt1hi, wt1lo, 256);
    k_wprep<<<(128 * 128 + 255) / 256, 256, 0, stream>>>(W2, wt2hi, wt2lo, 128);

    hipMemsetAsync(cnt, 0, (size_t)n * 4, stream);
    k_count<<<(E + 255) / 256, 256, 0, stream>>>(col, cnt, E);
    k_dinv<<<nb, 256, 0, stream>>>(cnt, dinv, n);
    k_scan_block<<<nb, 256, 0, stream>>>(cnt, offs, bsum, n);
    k_scan_sums<<<1, 512, 0, stream>>>(bsum, nb);
    k_scan_add<<<nb, 256, 0, stream>>>(offs, bsum, cnt, n);
    hipMemsetAsync(cnt, 0, (size_t)n * 4, stream);  // reuse as cursor
    k_fill<<<(E + 255) / 256, 256, 0, stream>>>(row, col, offs, cnt, dinv, pair, E);

    int aggBlocks = (n + 7) / 8;
    int gemmBlocks = (n + 127) / 128;
    // layer 1: h = x@W1 (bf16) ; g = relu(agg(h) + b1) (f32)
    k_gemm_mfma<256><<<gemmBlocks, 256, 0, stream>>>(x, wt1hi, wt1lo, bufH, n);
    k_agg<true><<<aggBlocks, 256, 0, stream>>>(bufH, dinv, offs, pair, b1, bufG, n);
    // layer 2: h = g@W2 (bf16) ; out = agg(h) + b2 (f32)
    k_gemm_mfma<128><<<gemmBlocks, 256, 0, stream>>>(bufG, wt2hi, wt2lo, bufH, n);
    k_agg<false><<<aggBlocks, 256, 0, stream>>>(bufH, dinv, offs, pair, b2, (float*)d_out, n);
}

// Round 7
// 270.055 us; speedup vs baseline: 2.3032x; 1.3717x over previous
//
#include <hip/hip_runtime.h>

// GCN encoder: 2x GCNConv (PyG semantics: self-loops, symmetric norm, aggregate at col)
// x:[100000,256] f32, W1:[256,128], b1:[128], W2:[128,128], b2:[128], edge_index:[2,1600000] int
// out:[100000,128] f32
//
// Pipeline: bucketed CSR build (no global atomics, coalesced scatter) ->
//   GEMM1 (hi/lo bf16 MFMA, epilogue pre-scales by dinv[row], bf16 out) ->
//   agg1 (weight-free gather-sum, *dinv[i], +b1, relu) -> GEMM2 -> agg2 -> f32 out.

#define NN 100000
#define NH 128
#define NB 196     // buckets: bucket = col >> 9 (512 nodes each)
#define SB 256     // hist/scatter blocks

__device__ __forceinline__ float bf2f(unsigned int u) { return __uint_as_float(u << 16); }
__device__ __forceinline__ unsigned short f2bf(float f) {
    unsigned int u = __float_as_uint(f);
    u = (u + 0x7fffu + ((u >> 16) & 1u)) >> 16;   // RNE
    return (unsigned short)u;
}

// async 16B/lane global->LDS DMA; lds dest = wave-uniform base + lane*16
__device__ __forceinline__ void dma16(const void* g, void* l) {
    __builtin_amdgcn_global_load_lds(
        (const __attribute__((address_space(1))) unsigned int*)g,
        (__attribute__((address_space(3))) unsigned int*)l, 16, 0, 0);
}

// ---------------- bucketed CSR build ----------------
// Pass 1: per-block bucket histogram (LDS atomics only)
__global__ __launch_bounds__(256) void k_hist(const int* __restrict__ col,
                                              int* __restrict__ blockCnt, int E, int chb) {
    __shared__ int h[NB];
    int t = threadIdx.x, blk = blockIdx.x;
    if (t < NB) h[t] = 0;
    __syncthreads();
    int s = blk * chb, en = min(E, s + chb);
    for (int e = s + t; e < en; e += 256) atomicAdd(&h[col[e] >> 9], 1);
    __syncthreads();
    if (t < NB) blockCnt[t * SB + blk] = h[t];
}

// Pass 2: bucket totals + exclusive scan -> base[NB+1]
__global__ __launch_bounds__(256) void k_base(const int* __restrict__ blockCnt,
                                              int* __restrict__ base) {
    __shared__ int s[256];
    int t = threadIdx.x;
    int tot = 0;
    if (t < NB)
        for (int j = 0; j < SB; ++j) tot += blockCnt[t * SB + j];
    s[t] = tot;
    __syncthreads();
    for (int off = 1; off < 256; off <<= 1) {
        int v = (t >= off) ? s[t - off] : 0;
        __syncthreads();
        s[t] += v;
        __syncthreads();
    }
    if (t < NB) base[t] = s[t] - tot;
    if (t == NB - 1) base[NB] = s[t];
}

// Pass 3: per-bucket exclusive scan over blocks -> absolute blockOff
__global__ __launch_bounds__(256) void k_bscan(const int* __restrict__ blockCnt,
                                               const int* __restrict__ base,
                                               int* __restrict__ blockOff) {
    __shared__ int s[256];
    int t = threadIdx.x, b = blockIdx.x;
    int v = blockCnt[b * SB + t];
    s[t] = v;
    __syncthreads();
    for (int off = 1; off < 256; off <<= 1) {
        int u = (t >= off) ? s[t - off] : 0;
        __syncthreads();
        s[t] += u;
        __syncthreads();
    }
    blockOff[b * SB + t] = base[b] + s[t] - v;
}

// Pass 4: scatter packed (src | local_col<<17) into contiguous bucket streams
__global__ __launch_bounds__(256) void k_scatter(const int* __restrict__ row,
                                                 const int* __restrict__ col,
                                                 const int* __restrict__ blockOff,
                                                 unsigned int* __restrict__ pairs,
                                                 int E, int chb) {
    __shared__ int cur[NB];
    __shared__ int bof[NB];
    int t = threadIdx.x, blk = blockIdx.x;
    if (t < NB) {
        cur[t] = 0;
        bof[t] = blockOff[t * SB + blk];
    }
    __syncthreads();
    int s = blk * chb, en = min(E, s + chb);
    for (int e = s + t; e < en; e += 256) {
        int c = col[e];
        int b = c >> 9;
        int r = atomicAdd(&cur[b], 1);
        pairs[bof[b] + r] = (unsigned int)row[e] | ((unsigned int)(c & 511) << 17);
    }
}

// Pass 5: exact binning within each bucket -> final CSR src list, offs, dinv
__global__ __launch_bounds__(512) void k_bin(const unsigned int* __restrict__ pairs,
                                             const int* __restrict__ base,
                                             unsigned int* __restrict__ csr,
                                             int* __restrict__ offs,
                                             float* __restrict__ dinv, int n) {
    __shared__ int cnt[512];
    __shared__ int s[512];
    int t = threadIdx.x, b = blockIdx.x;
    cnt[t] = 0;
    __syncthreads();
    int e0 = base[b], e1 = base[b + 1];
    for (int i = e0 + t; i < e1; i += 512) atomicAdd(&cnt[pairs[i] >> 17], 1);
    __syncthreads();
    int v = cnt[t];
    int node = b * 512 + t;
    if (node < n) dinv[node] = rsqrtf(1.0f + (float)v);   // deg = 1 (self-loop) + in-degree
    s[t] = v;
    __syncthreads();
    for (int off = 1; off < 512; off <<= 1) {
        int u = (t >= off) ? s[t - off] : 0;
        __syncthreads();
        s[t] += u;
        __syncthreads();
    }
    int excl = s[t] - v;
    if (node <= n) offs[node] = e0 + excl;
    __syncthreads();
    cnt[t] = e0 + excl;    // absolute cursor
    __syncthreads();
    for (int i = e0 + t; i < e1; i += 512) {
        unsigned int p = pairs[i];
        int d = atomicAdd(&cnt[p >> 17], 1);
        csr[d] = p & 0x1FFFFu;
    }
}

// ---------------- W prepass: f32 [K][128] -> transposed bf16 hi/lo [128][K] ----------------
__global__ void k_wprep(const float* __restrict__ W, unsigned short* __restrict__ Thi,
                        unsigned short* __restrict__ Tlo, int K) {
    int idx = blockIdx.x * 256 + threadIdx.x;
    if (idx >= K * 128) return;
    int k = idx >> 7, c = idx & 127;
    float w = W[idx];
    unsigned int u = __float_as_uint(w) & 0xffff0000u;   // truncate hi
    float rem = w - __uint_as_float(u);
    Thi[(size_t)c * K + k] = (unsigned short)(u >> 16);
    Tlo[(size_t)c * K + k] = (unsigned short)(__float_as_uint(rem) >> 16);
}

// ---------------- MFMA GEMM: C[M,128](bf16) = (A[M,K](f32) @ W[K,128]) * dinv[row] ----------------
// hi/lo bf16 split: AhBh + AlBh + AhBl ~= f32-accurate. Epilogue pre-scales rows by dinv.
// Block = 128 rows x 128 cols, 4 waves, BK=32, double-buffered LDS via global_load_lds.
template <int K>
__global__ __launch_bounds__(256) void k_gemm_mfma(const float* __restrict__ A,
                                                   const unsigned short* __restrict__ Bhi,
                                                   const unsigned short* __restrict__ Blo,
                                                   const float* __restrict__ dinv,
                                                   unsigned short* __restrict__ C, int M) {
    using bf16x8 = __attribute__((ext_vector_type(8))) short;
    using f32x4  = __attribute__((ext_vector_type(4))) float;
    constexpr int T = K / 32;
    __shared__ uint4 sA4[2][1024];     // [buf][kb*256 + j*128 + row]  (f32 A, 16KB/buf)
    __shared__ uint4 sB4[2][2][512];   // [buf][hi/lo][kb*128 + col]   (bf16 B, 8KB each)

    const int lane = threadIdx.x & 63;
    const int wv   = threadIdx.x >> 6;       // 0..3
    const int r    = lane & 15;              // row/col within frag
    const int kb   = lane >> 4;              // k-block 0..3
    const int rowBase = blockIdx.x * 128;

    f32x4 acc[2][8];
#pragma unroll
    for (int m = 0; m < 2; ++m)
#pragma unroll
        for (int t = 0; t < 8; ++t) acc[m][t] = (f32x4){0.f, 0.f, 0.f, 0.f};

#pragma unroll
    for (int ks = 0; ks < T; ++ks) {
        const int buf = ks & 1;
        const int kk  = ks * 32;
        // ---- stage A tile: 1024 slots, 4 chunks/wave ----
#pragma unroll
        for (int c = 0; c < 4; ++c) {
            int sb = wv * 256 + c * 64;            // wave-uniform slot base
            int s  = sb + lane;
            int akb = s >> 8, aj = (s >> 7) & 1, ar = s & 127;
            int gr = rowBase + ar; if (gr >= M) gr = M - 1;
            dma16(A + (size_t)gr * K + kk + akb * 8 + aj * 4, &sA4[buf][sb]);
        }
        // ---- stage B hi/lo: 512 slots each, 2 chunks/wave ----
#pragma unroll
        for (int hl = 0; hl < 2; ++hl) {
            const unsigned short* Bp = hl ? Blo : Bhi;
#pragma unroll
            for (int c = 0; c < 2; ++c) {
                int sb = wv * 128 + c * 64;
                int s  = sb + lane;
                int bkb = s >> 7, bcol = s & 127;
                dma16(Bp + (size_t)bcol * K + kk + bkb * 8, &sB4[buf][hl][sb]);
            }
        }
        __syncthreads();   // full vmcnt/lgkmcnt drain: tile ready, prev reads done
        // ---- A frags: convert f32 -> bf16 hi/lo ----
        bf16x8 ah[2], al[2];
#pragma unroll
        for (int m = 0; m < 2; ++m) {
            int rowl = wv * 32 + m * 16 + r;
            uint4 u0 = sA4[buf][kb * 256 + rowl];          // k = kb*8 + 0..3
            uint4 u1 = sA4[buf][kb * 256 + 128 + rowl];    // k = kb*8 + 4..7
            float f[8];
            *(uint4*)&f[0] = u0;
            *(uint4*)&f[4] = u1;
#pragma unroll
            for (int j = 0; j < 8; ++j) {
                float x = f[j];
                unsigned int u = __float_as_uint(x) & 0xffff0000u;
                ah[m][j] = (short)(u >> 16);
                al[m][j] = (short)(__float_as_uint(x - __uint_as_float(u)) >> 16);
            }
        }
        // ---- B frags + MFMAs ----
#pragma unroll
        for (int t = 0; t < 8; ++t) {
            int col = t * 16 + r;
            bf16x8 bh = *(const bf16x8*)&sB4[buf][0][kb * 128 + col];
            bf16x8 bl = *(const bf16x8*)&sB4[buf][1][kb * 128 + col];
#pragma unroll
            for (int m = 0; m < 2; ++m) {
                acc[m][t] = __builtin_amdgcn_mfma_f32_16x16x32_bf16(ah[m], bh, acc[m][t], 0, 0, 0);
                acc[m][t] = __builtin_amdgcn_mfma_f32_16x16x32_bf16(al[m], bh, acc[m][t], 0, 0, 0);
                acc[m][t] = __builtin_amdgcn_mfma_f32_16x16x32_bf16(ah[m], bl, acc[m][t], 0, 0, 0);
            }
        }
    }
    // C/D layout (m89-verified): col = lane&15, row = (lane>>4)*4 + reg; scale by dinv[row]
    const int wrow = rowBase + wv * 32;
#pragma unroll
    for (int m = 0; m < 2; ++m) {
#pragma unroll
        for (int q = 0; q < 4; ++q) {
            int orow = wrow + m * 16 + kb * 4 + q;
            if (orow < M) {
                float dv = dinv[orow];
#pragma unroll
                for (int t = 0; t < 8; ++t)
                    C[(size_t)orow * 128 + t * 16 + r] = f2bf(acc[m][t][q] * dv);
            }
        }
    }
}

// ---------------- aggregate ----------------
// out[i] = dinv[i] * (sum_{e: col=i} hs[src_e] + hs[i]) + b   (hs = h*dinv, bf16)
// 32 lanes per node (4 feats/lane, uint2=8B), 2 nodes per wave, edge loop unrolled 4x.
template <bool RELU>
__global__ __launch_bounds__(256) void k_agg(const unsigned short* __restrict__ hb,
                                             const float* __restrict__ dinv,
                                             const int* __restrict__ off,
                                             const unsigned int* __restrict__ csr,
                                             const float* __restrict__ bias,
                                             float* __restrict__ out, int n) {
    int node = blockIdx.x * 8 + (threadIdx.x >> 5);
    int lane = threadIdx.x & 31;
    if (node >= n) return;
    float di = dinv[node];
    uint2 us = *(const uint2*)(hb + ((size_t)node << 7) + lane * 4);
    float a0 = bf2f(us.x & 0xffffu);
    float a1 = bf2f(us.x >> 16);
    float a2 = bf2f(us.y & 0xffffu);
    float a3 = bf2f(us.y >> 16);
    int e  = off[node];
    int e1 = off[node + 1];
    for (; e + 4 <= e1; e += 4) {
        unsigned int s0 = csr[e + 0];
        unsigned int s1 = csr[e + 1];
        unsigned int s2 = csr[e + 2];
        unsigned int s3 = csr[e + 3];
        uint2 u0 = *(const uint2*)(hb + ((size_t)s0 << 7) + lane * 4);
        uint2 u1 = *(const uint2*)(hb + ((size_t)s1 << 7) + lane * 4);
        uint2 u2 = *(const uint2*)(hb + ((size_t)s2 << 7) + lane * 4);
        uint2 u3 = *(const uint2*)(hb + ((size_t)s3 << 7) + lane * 4);
        a0 += bf2f(u0.x & 0xffffu); a1 += bf2f(u0.x >> 16);
        a2 += bf2f(u0.y & 0xffffu); a3 += bf2f(u0.y >> 16);
        a0 += bf2f(u1.x & 0xffffu); a1 += bf2f(u1.x >> 16);
        a2 += bf2f(u1.y & 0xffffu); a3 += bf2f(u1.y >> 16);
        a0 += bf2f(u2.x & 0xffffu); a1 += bf2f(u2.x >> 16);
        a2 += bf2f(u2.y & 0xffffu); a3 += bf2f(u2.y >> 16);
        a0 += bf2f(u3.x & 0xffffu); a1 += bf2f(u3.x >> 16);
        a2 += bf2f(u3.y & 0xffffu); a3 += bf2f(u3.y >> 16);
    }
    for (; e < e1; ++e) {
        unsigned int s = csr[e];
        uint2 u = *(const uint2*)(hb + ((size_t)s << 7) + lane * 4);
        a0 += bf2f(u.x & 0xffffu); a1 += bf2f(u.x >> 16);
        a2 += bf2f(u.y & 0xffffu); a3 += bf2f(u.y >> 16);
    }
    float4 b = *(const float4*)&bias[lane * 4];
    a0 = a0 * di + b.x;
    a1 = a1 * di + b.y;
    a2 = a2 * di + b.z;
    a3 = a3 * di + b.w;
    if (RELU) {
        a0 = fmaxf(a0, 0.f); a1 = fmaxf(a1, 0.f);
        a2 = fmaxf(a2, 0.f); a3 = fmaxf(a3, 0.f);
    }
    *(float4*)(out + ((size_t)node << 7) + lane * 4) = make_float4(a0, a1, a2, a3);
}

extern "C" void kernel_launch(void* const* d_in, const int* in_sizes, int n_in,
                              void* d_out, int out_size, void* d_ws, size_t ws_size,
                              hipStream_t stream) {
    const float* x  = (const float*)d_in[0];
    const float* W1 = (const float*)d_in[1];
    const float* b1 = (const float*)d_in[2];
    const float* W2 = (const float*)d_in[3];
    const float* b2 = (const float*)d_in[4];
    const int*   ei = (const int*)d_in[5];

    const int n = NN;
    const int E = in_sizes[5] / 2;
    const int* row = ei;        // sources
    const int* col = ei + E;    // targets

    char* ws = (char*)d_ws;
    size_t o = 0;
    auto alloc = [&](size_t bytes) {
        void* p = ws + o;
        o = (o + bytes + 255) & ~(size_t)255;
        return p;
    };
    int*            blockCnt = (int*)alloc((size_t)NB * SB * 4);
    int*            blockOff = (int*)alloc((size_t)NB * SB * 4);
    int*            base     = (int*)alloc((size_t)(NB + 1) * 4);
    int*            offs     = (int*)alloc((size_t)(n + 1) * 4);
    float*          dinv     = (float*)alloc((size_t)n * 4);
    unsigned int*   pairs    = (unsigned int*)alloc((size_t)E * 4);
    unsigned int*   csr      = (unsigned int*)alloc((size_t)E * 4);
    unsigned short* bufH     = (unsigned short*)alloc((size_t)n * NH * 2);  // bf16 hs
    float*          bufG     = (float*)alloc((size_t)n * NH * 4);           // f32 g
    unsigned short* wt1hi    = (unsigned short*)alloc(256 * 128 * 2);
    unsigned short* wt1lo    = (unsigned short*)alloc(256 * 128 * 2);
    unsigned short* wt2hi    = (unsigned short*)alloc(128 * 128 * 2);
    unsigned short* wt2lo    = (unsigned short*)alloc(128 * 128 * 2);

    const int chb = (E + SB - 1) / SB;

    // W prepasses (independent of CSR build)
    k_wprep<<<(256 * 128 + 255) / 256, 256, 0, stream>>>(W1, wt1hi, wt1lo, 256);
    k_wprep<<<(128 * 128 + 255) / 256, 256, 0, stream>>>(W2, wt2hi, wt2lo, 128);

    // bucketed CSR build
    k_hist<<<SB, 256, 0, stream>>>(col, blockCnt, E, chb);
    k_base<<<1, 256, 0, stream>>>(blockCnt, base);
    k_bscan<<<NB, 256, 0, stream>>>(blockCnt, base, blockOff);
    k_scatter<<<SB, 256, 0, stream>>>(row, col, blockOff, pairs, E, chb);
    k_bin<<<NB, 512, 0, stream>>>(pairs, base, csr, offs, dinv, n);

    int aggBlocks = (n + 7) / 8;
    int gemmBlocks = (n + 127) / 128;
    // layer 1: hs = (x@W1)*dinv (bf16) ; g = relu(dinv*(agg(hs)+hs) + b1) (f32)
    k_gemm_mfma<256><<<gemmBlocks, 256, 0, stream>>>(x, wt1hi, wt1lo, dinv, bufH, n);
    k_agg<true><<<aggBlocks, 256, 0, stream>>>(bufH, dinv, offs, csr, b1, bufG, n);
    // layer 2: hs = (g@W2)*dinv (bf16) ; out = dinv*(agg(hs)+hs) + b2 (f32)
    k_gemm_mfma<128><<<gemmBlocks, 256, 0, stream>>>(bufG, wt2hi, wt2lo, dinv, bufH, n);
    k_agg<false><<<aggBlocks, 256, 0, stream>>>(bufH, dinv, offs, csr, b2, (float*)d_out, n);
}

// Round 8
// 254.829 us; speedup vs baseline: 2.4408x; 1.0597x over previous
//
#include <hip/hip_runtime.h>

// GCN encoder: 2x GCNConv (PyG semantics: self-loops, symmetric norm, aggregate at col)
// x:[100000,256] f32, W1:[256,128], b1:[128], W2:[128,128], b2:[128], edge_index:[2,1600000] int
// out:[100000,128] f32
//
// Pipeline: bucketed CSR build -> GEMM1 (f32 A hi/lo-split MFMA, *dinv[row], bf16 out) ->
//   agg1 (16-lane/node gather-sum, *dinv, +b1, relu, bf16 out) ->
//   GEMM2 (bf16 A direct, *dinv[row], bf16 out) -> agg2 (f32 out).

#define NN 100000
#define NH 128
#define NB 196     // buckets: bucket = col >> 9 (512 nodes each)
#define SB 256     // hist/scatter blocks

__device__ __forceinline__ float bf2f(unsigned int u) { return __uint_as_float(u << 16); }
__device__ __forceinline__ unsigned short f2bf(float f) {
    unsigned int u = __float_as_uint(f);
    u = (u + 0x7fffu + ((u >> 16) & 1u)) >> 16;   // RNE
    return (unsigned short)u;
}

// async 16B/lane global->LDS DMA; lds dest = wave-uniform base + lane*16
__device__ __forceinline__ void dma16(const void* g, void* l) {
    __builtin_amdgcn_global_load_lds(
        (const __attribute__((address_space(1))) unsigned int*)g,
        (__attribute__((address_space(3))) unsigned int*)l, 16, 0, 0);
}

// ---------------- bucketed CSR build ----------------
__global__ __launch_bounds__(256) void k_hist(const int* __restrict__ col,
                                              int* __restrict__ blockCnt, int E, int chb) {
    __shared__ int h[NB];
    int t = threadIdx.x, blk = blockIdx.x;
    if (t < NB) h[t] = 0;
    __syncthreads();
    int s = blk * chb, en = min(E, s + chb);
    for (int e = s + t; e < en; e += 256) atomicAdd(&h[col[e] >> 9], 1);
    __syncthreads();
    if (t < NB) blockCnt[t * SB + blk] = h[t];
}

__global__ __launch_bounds__(256) void k_base(const int* __restrict__ blockCnt,
                                              int* __restrict__ base) {
    __shared__ int s[256];
    int t = threadIdx.x;
    int tot = 0;
    if (t < NB)
        for (int j = 0; j < SB; ++j) tot += blockCnt[t * SB + j];
    s[t] = tot;
    __syncthreads();
    for (int off = 1; off < 256; off <<= 1) {
        int v = (t >= off) ? s[t - off] : 0;
        __syncthreads();
        s[t] += v;
        __syncthreads();
    }
    if (t < NB) base[t] = s[t] - tot;
    if (t == NB - 1) base[NB] = s[t];
}

__global__ __launch_bounds__(256) void k_bscan(const int* __restrict__ blockCnt,
                                               const int* __restrict__ base,
                                               int* __restrict__ blockOff) {
    __shared__ int s[256];
    int t = threadIdx.x, b = blockIdx.x;
    int v = blockCnt[b * SB + t];
    s[t] = v;
    __syncthreads();
    for (int off = 1; off < 256; off <<= 1) {
        int u = (t >= off) ? s[t - off] : 0;
        __syncthreads();
        s[t] += u;
        __syncthreads();
    }
    blockOff[b * SB + t] = base[b] + s[t] - v;
}

__global__ __launch_bounds__(256) void k_scatter(const int* __restrict__ row,
                                                 const int* __restrict__ col,
                                                 const int* __restrict__ blockOff,
                                                 unsigned int* __restrict__ pairs,
                                                 int E, int chb) {
    __shared__ int cur[NB];
    __shared__ int bof[NB];
    int t = threadIdx.x, blk = blockIdx.x;
    if (t < NB) {
        cur[t] = 0;
        bof[t] = blockOff[t * SB + blk];
    }
    __syncthreads();
    int s = blk * chb, en = min(E, s + chb);
    for (int e = s + t; e < en; e += 256) {
        int c = col[e];
        int b = c >> 9;
        int r = atomicAdd(&cur[b], 1);
        pairs[bof[b] + r] = (unsigned int)row[e] | ((unsigned int)(c & 511) << 17);
    }
}

__global__ __launch_bounds__(512) void k_bin(const unsigned int* __restrict__ pairs,
                                             const int* __restrict__ base,
                                             unsigned int* __restrict__ csr,
                                             int* __restrict__ offs,
                                             float* __restrict__ dinv, int n) {
    __shared__ int cnt[512];
    __shared__ int s[512];
    int t = threadIdx.x, b = blockIdx.x;
    cnt[t] = 0;
    __syncthreads();
    int e0 = base[b], e1 = base[b + 1];
    for (int i = e0 + t; i < e1; i += 512) atomicAdd(&cnt[pairs[i] >> 17], 1);
    __syncthreads();
    int v = cnt[t];
    int node = b * 512 + t;
    if (node < n) dinv[node] = rsqrtf(1.0f + (float)v);   // deg = 1 (self-loop) + in-degree
    s[t] = v;
    __syncthreads();
    for (int off = 1; off < 512; off <<= 1) {
        int u = (t >= off) ? s[t - off] : 0;
        __syncthreads();
        s[t] += u;
        __syncthreads();
    }
    int excl = s[t] - v;
    if (node <= n) offs[node] = e0 + excl;
    __syncthreads();
    cnt[t] = e0 + excl;    // absolute cursor
    __syncthreads();
    for (int i = e0 + t; i < e1; i += 512) {
        unsigned int p = pairs[i];
        int d = atomicAdd(&cnt[p >> 17], 1);
        csr[d] = p & 0x1FFFFu;
    }
}

// ---------------- W prepass: f32 [K][128] -> transposed bf16 hi/lo [128][K] ----------------
__global__ void k_wprep(const float* __restrict__ W, unsigned short* __restrict__ Thi,
                        unsigned short* __restrict__ Tlo, int K) {
    int idx = blockIdx.x * 256 + threadIdx.x;
    if (idx >= K * 128) return;
    int k = idx >> 7, c = idx & 127;
    float w = W[idx];
    unsigned int u = __float_as_uint(w) & 0xffff0000u;   // truncate hi
    float rem = w - __uint_as_float(u);
    Thi[(size_t)c * K + k] = (unsigned short)(u >> 16);
    Tlo[(size_t)c * K + k] = (unsigned short)(__float_as_uint(rem) >> 16);
}

// ---------------- GEMM1: C[M,128](bf16) = (A[M,K](f32) @ W) * dinv[row] ----------------
template <int K>
__global__ __launch_bounds__(256) void k_gemm_mfma(const float* __restrict__ A,
                                                   const unsigned short* __restrict__ Bhi,
                                                   const unsigned short* __restrict__ Blo,
                                                   const float* __restrict__ dinv,
                                                   unsigned short* __restrict__ C, int M) {
    using bf16x8 = __attribute__((ext_vector_type(8))) short;
    using f32x4  = __attribute__((ext_vector_type(4))) float;
    constexpr int T = K / 32;
    __shared__ uint4 sA4[2][1024];     // [buf][kb*256 + j*128 + row]  (f32 A)
    __shared__ uint4 sB4[2][2][512];   // [buf][hi/lo][kb*128 + col]

    const int lane = threadIdx.x & 63;
    const int wv   = threadIdx.x >> 6;
    const int r    = lane & 15;
    const int kb   = lane >> 4;
    const int rowBase = blockIdx.x * 128;

    f32x4 acc[2][8];
#pragma unroll
    for (int m = 0; m < 2; ++m)
#pragma unroll
        for (int t = 0; t < 8; ++t) acc[m][t] = (f32x4){0.f, 0.f, 0.f, 0.f};

#pragma unroll
    for (int ks = 0; ks < T; ++ks) {
        const int buf = ks & 1;
        const int kk  = ks * 32;
#pragma unroll
        for (int c = 0; c < 4; ++c) {
            int sb = wv * 256 + c * 64;
            int s  = sb + lane;
            int akb = s >> 8, aj = (s >> 7) & 1, ar = s & 127;
            int gr = rowBase + ar; if (gr >= M) gr = M - 1;
            dma16(A + (size_t)gr * K + kk + akb * 8 + aj * 4, &sA4[buf][sb]);
        }
#pragma unroll
        for (int hl = 0; hl < 2; ++hl) {
            const unsigned short* Bp = hl ? Blo : Bhi;
#pragma unroll
            for (int c = 0; c < 2; ++c) {
                int sb = wv * 128 + c * 64;
                int s  = sb + lane;
                int bkb = s >> 7, bcol = s & 127;
                dma16(Bp + (size_t)bcol * K + kk + bkb * 8, &sB4[buf][hl][sb]);
            }
        }
        __syncthreads();
        bf16x8 ah[2], al[2];
#pragma unroll
        for (int m = 0; m < 2; ++m) {
            int rowl = wv * 32 + m * 16 + r;
            uint4 u0 = sA4[buf][kb * 256 + rowl];
            uint4 u1 = sA4[buf][kb * 256 + 128 + rowl];
            float f[8];
            *(uint4*)&f[0] = u0;
            *(uint4*)&f[4] = u1;
#pragma unroll
            for (int j = 0; j < 8; ++j) {
                float x = f[j];
                unsigned int u = __float_as_uint(x) & 0xffff0000u;
                ah[m][j] = (short)(u >> 16);
                al[m][j] = (short)(__float_as_uint(x - __uint_as_float(u)) >> 16);
            }
        }
#pragma unroll
        for (int t = 0; t < 8; ++t) {
            int col = t * 16 + r;
            bf16x8 bh = *(const bf16x8*)&sB4[buf][0][kb * 128 + col];
            bf16x8 bl = *(const bf16x8*)&sB4[buf][1][kb * 128 + col];
#pragma unroll
            for (int m = 0; m < 2; ++m) {
                acc[m][t] = __builtin_amdgcn_mfma_f32_16x16x32_bf16(ah[m], bh, acc[m][t], 0, 0, 0);
                acc[m][t] = __builtin_amdgcn_mfma_f32_16x16x32_bf16(al[m], bh, acc[m][t], 0, 0, 0);
                acc[m][t] = __builtin_amdgcn_mfma_f32_16x16x32_bf16(ah[m], bl, acc[m][t], 0, 0, 0);
            }
        }
    }
    const int wrow = rowBase + wv * 32;
#pragma unroll
    for (int m = 0; m < 2; ++m) {
#pragma unroll
        for (int q = 0; q < 4; ++q) {
            int orow = wrow + m * 16 + kb * 4 + q;
            if (orow < M) {
                float dv = dinv[orow];
#pragma unroll
                for (int t = 0; t < 8; ++t)
                    C[(size_t)orow * 128 + t * 16 + r] = f2bf(acc[m][t][q] * dv);
            }
        }
    }
}

// ---------------- GEMM2: C[M,128](bf16) = (A[M,K](bf16) @ W) * dinv[row] ----------------
template <int K>
__global__ __launch_bounds__(256) void k_gemm_bf16(const unsigned short* __restrict__ A,
                                                   const unsigned short* __restrict__ Bhi,
                                                   const unsigned short* __restrict__ Blo,
                                                   const float* __restrict__ dinv,
                                                   unsigned short* __restrict__ C, int M) {
    using bf16x8 = __attribute__((ext_vector_type(8))) short;
    using f32x4  = __attribute__((ext_vector_type(4))) float;
    constexpr int T = K / 32;
    __shared__ uint4 sA2[2][512];      // [buf][kb*128 + row] (bf16 A)
    __shared__ uint4 sB4[2][2][512];   // [buf][hi/lo][kb*128 + col]

    const int lane = threadIdx.x & 63;
    const int wv   = threadIdx.x >> 6;
    const int r    = lane & 15;
    const int kb   = lane >> 4;
    const int rowBase = blockIdx.x * 128;

    f32x4 acc[2][8];
#pragma unroll
    for (int m = 0; m < 2; ++m)
#pragma unroll
        for (int t = 0; t < 8; ++t) acc[m][t] = (f32x4){0.f, 0.f, 0.f, 0.f};

#pragma unroll
    for (int ks = 0; ks < T; ++ks) {
        const int buf = ks & 1;
        const int kk  = ks * 32;
#pragma unroll
        for (int c = 0; c < 2; ++c) {
            int sb = wv * 128 + c * 64;
            int s  = sb + lane;
            int akb = s >> 7, ar = s & 127;
            int gr = rowBase + ar; if (gr >= M) gr = M - 1;
            dma16(A + (size_t)gr * K + kk + akb * 8, &sA2[buf][sb]);
        }
#pragma unroll
        for (int hl = 0; hl < 2; ++hl) {
            const unsigned short* Bp = hl ? Blo : Bhi;
#pragma unroll
            for (int c = 0; c < 2; ++c) {
                int sb = wv * 128 + c * 64;
                int s  = sb + lane;
                int bkb = s >> 7, bcol = s & 127;
                dma16(Bp + (size_t)bcol * K + kk + bkb * 8, &sB4[buf][hl][sb]);
            }
        }
        __syncthreads();
#pragma unroll
        for (int t = 0; t < 8; ++t) {
            int col = t * 16 + r;
            bf16x8 bh = *(const bf16x8*)&sB4[buf][0][kb * 128 + col];
            bf16x8 bl = *(const bf16x8*)&sB4[buf][1][kb * 128 + col];
#pragma unroll
            for (int m = 0; m < 2; ++m) {
                bf16x8 a = *(const bf16x8*)&sA2[buf][kb * 128 + wv * 32 + m * 16 + r];
                acc[m][t] = __builtin_amdgcn_mfma_f32_16x16x32_bf16(a, bh, acc[m][t], 0, 0, 0);
                acc[m][t] = __builtin_amdgcn_mfma_f32_16x16x32_bf16(a, bl, acc[m][t], 0, 0, 0);
            }
        }
    }
    const int wrow = rowBase + wv * 32;
#pragma unroll
    for (int m = 0; m < 2; ++m) {
#pragma unroll
        for (int q = 0; q < 4; ++q) {
            int orow = wrow + m * 16 + kb * 4 + q;
            if (orow < M) {
                float dv = dinv[orow];
#pragma unroll
                for (int t = 0; t < 8; ++t)
                    C[(size_t)orow * 128 + t * 16 + r] = f2bf(acc[m][t][q] * dv);
            }
        }
    }
}

// ---------------- aggregate ----------------
// out[i] = dinv[i] * (sum_{e: col=i} hs[src_e] + hs[i]) + b   (hs = h*dinv, bf16)
// 16 lanes/node (8 feats/lane, uint4=16B => one load per 256B row), 4 nodes/wave,
// edge loop unrolled 4x -> 16 independent row gathers in flight per wave.
template <bool RELU, bool BF16OUT>
__global__ __launch_bounds__(256) void k_agg(const unsigned short* __restrict__ hb,
                                             const float* __restrict__ dinv,
                                             const int* __restrict__ off,
                                             const unsigned int* __restrict__ csr,
                                             const float* __restrict__ bias,
                                             void* __restrict__ outv, int n) {
    int gid  = blockIdx.x * 256 + threadIdx.x;
    int node = gid >> 4;
    int lane = gid & 15;
    if (node >= n) return;
    float di = dinv[node];
    uint4 us = *(const uint4*)(hb + ((size_t)node << 7) + lane * 8);
    float a[8];
    a[0] = bf2f(us.x & 0xffffu); a[1] = bf2f(us.x >> 16);
    a[2] = bf2f(us.y & 0xffffu); a[3] = bf2f(us.y >> 16);
    a[4] = bf2f(us.z & 0xffffu); a[5] = bf2f(us.z >> 16);
    a[6] = bf2f(us.w & 0xffffu); a[7] = bf2f(us.w >> 16);
    int e  = off[node];
    int e1 = off[node + 1];
    for (; e + 4 <= e1; e += 4) {
        unsigned int s0 = csr[e + 0];
        unsigned int s1 = csr[e + 1];
        unsigned int s2 = csr[e + 2];
        unsigned int s3 = csr[e + 3];
        uint4 u0 = *(const uint4*)(hb + ((size_t)s0 << 7) + lane * 8);
        uint4 u1 = *(const uint4*)(hb + ((size_t)s1 << 7) + lane * 8);
        uint4 u2 = *(const uint4*)(hb + ((size_t)s2 << 7) + lane * 8);
        uint4 u3 = *(const uint4*)(hb + ((size_t)s3 << 7) + lane * 8);
        a[0] += bf2f(u0.x & 0xffffu); a[1] += bf2f(u0.x >> 16);
        a[2] += bf2f(u0.y & 0xffffu); a[3] += bf2f(u0.y >> 16);
        a[4] += bf2f(u0.z & 0xffffu); a[5] += bf2f(u0.z >> 16);
        a[6] += bf2f(u0.w & 0xffffu); a[7] += bf2f(u0.w >> 16);
        a[0] += bf2f(u1.x & 0xffffu); a[1] += bf2f(u1.x >> 16);
        a[2] += bf2f(u1.y & 0xffffu); a[3] += bf2f(u1.y >> 16);
        a[4] += bf2f(u1.z & 0xffffu); a[5] += bf2f(u1.z >> 16);
        a[6] += bf2f(u1.w & 0xffffu); a[7] += bf2f(u1.w >> 16);
        a[0] += bf2f(u2.x & 0xffffu); a[1] += bf2f(u2.x >> 16);
        a[2] += bf2f(u2.y & 0xffffu); a[3] += bf2f(u2.y >> 16);
        a[4] += bf2f(u2.z & 0xffffu); a[5] += bf2f(u2.z >> 16);
        a[6] += bf2f(u2.w & 0xffffu); a[7] += bf2f(u2.w >> 16);
        a[0] += bf2f(u3.x & 0xffffu); a[1] += bf2f(u3.x >> 16);
        a[2] += bf2f(u3.y & 0xffffu); a[3] += bf2f(u3.y >> 16);
        a[4] += bf2f(u3.z & 0xffffu); a[5] += bf2f(u3.z >> 16);
        a[6] += bf2f(u3.w & 0xffffu); a[7] += bf2f(u3.w >> 16);
    }
    for (; e < e1; ++e) {
        unsigned int s = csr[e];
        uint4 u = *(const uint4*)(hb + ((size_t)s << 7) + lane * 8);
        a[0] += bf2f(u.x & 0xffffu); a[1] += bf2f(u.x >> 16);
        a[2] += bf2f(u.y & 0xffffu); a[3] += bf2f(u.y >> 16);
        a[4] += bf2f(u.z & 0xffffu); a[5] += bf2f(u.z >> 16);
        a[6] += bf2f(u.w & 0xffffu); a[7] += bf2f(u.w >> 16);
    }
    float4 b0 = *(const float4*)&bias[lane * 8];
    float4 b1 = *(const float4*)&bias[lane * 8 + 4];
    a[0] = a[0] * di + b0.x; a[1] = a[1] * di + b0.y;
    a[2] = a[2] * di + b0.z; a[3] = a[3] * di + b0.w;
    a[4] = a[4] * di + b1.x; a[5] = a[5] * di + b1.y;
    a[6] = a[6] * di + b1.z; a[7] = a[7] * di + b1.w;
    if (RELU) {
#pragma unroll
        for (int j = 0; j < 8; ++j) a[j] = fmaxf(a[j], 0.f);
    }
    if (BF16OUT) {
        uint4 o;
        o.x = (unsigned int)f2bf(a[0]) | ((unsigned int)f2bf(a[1]) << 16);
        o.y = (unsigned int)f2bf(a[2]) | ((unsigned int)f2bf(a[3]) << 16);
        o.z = (unsigned int)f2bf(a[4]) | ((unsigned int)f2bf(a[5]) << 16);
        o.w = (unsigned int)f2bf(a[6]) | ((unsigned int)f2bf(a[7]) << 16);
        *(uint4*)((unsigned short*)outv + ((size_t)node << 7) + lane * 8) = o;
    } else {
        float* op = (float*)outv + ((size_t)node << 7) + lane * 8;
        *(float4*)op       = make_float4(a[0], a[1], a[2], a[3]);
        *(float4*)(op + 4) = make_float4(a[4], a[5], a[6], a[7]);
    }
}

extern "C" void kernel_launch(void* const* d_in, const int* in_sizes, int n_in,
                              void* d_out, int out_size, void* d_ws, size_t ws_size,
                              hipStream_t stream) {
    const float* x  = (const float*)d_in[0];
    const float* W1 = (const float*)d_in[1];
    const float* b1 = (const float*)d_in[2];
    const float* W2 = (const float*)d_in[3];
    const float* b2 = (const float*)d_in[4];
    const int*   ei = (const int*)d_in[5];

    const int n = NN;
    const int E = in_sizes[5] / 2;
    const int* row = ei;        // sources
    const int* col = ei + E;    // targets

    char* ws = (char*)d_ws;
    size_t o = 0;
    auto alloc = [&](size_t bytes) {
        void* p = ws + o;
        o = (o + bytes + 255) & ~(size_t)255;
        return p;
    };
    int*            blockCnt = (int*)alloc((size_t)NB * SB * 4);
    int*            blockOff = (int*)alloc((size_t)NB * SB * 4);
    int*            base     = (int*)alloc((size_t)(NB + 1) * 4);
    int*            offs     = (int*)alloc((size_t)(n + 1) * 4);
    float*          dinv     = (float*)alloc((size_t)n * 4);
    unsigned int*   pairs    = (unsigned int*)alloc((size_t)E * 4);
    unsigned int*   csr      = (unsigned int*)alloc((size_t)E * 4);
    unsigned short* bufH     = (unsigned short*)alloc((size_t)n * NH * 2);  // bf16 hs
    unsigned short* bufG     = (unsigned short*)alloc((size_t)n * NH * 2);  // bf16 g
    unsigned short* wt1hi    = (unsigned short*)alloc(256 * 128 * 2);
    unsigned short* wt1lo    = (unsigned short*)alloc(256 * 128 * 2);
    unsigned short* wt2hi    = (unsigned short*)alloc(128 * 128 * 2);
    unsigned short* wt2lo    = (unsigned short*)alloc(128 * 128 * 2);

    const int chb = (E + SB - 1) / SB;

    // W prepasses (independent of CSR build)
    k_wprep<<<(256 * 128 + 255) / 256, 256, 0, stream>>>(W1, wt1hi, wt1lo, 256);
    k_wprep<<<(128 * 128 + 255) / 256, 256, 0, stream>>>(W2, wt2hi, wt2lo, 128);

    // bucketed CSR build
    k_hist<<<SB, 256, 0, stream>>>(col, blockCnt, E, chb);
    k_base<<<1, 256, 0, stream>>>(blockCnt, base);
    k_bscan<<<NB, 256, 0, stream>>>(blockCnt, base, blockOff);
    k_scatter<<<SB, 256, 0, stream>>>(row, col, blockOff, pairs, E, chb);
    k_bin<<<NB, 512, 0, stream>>>(pairs, base, csr, offs, dinv, n);

    int aggBlocks = (n + 15) / 16;
    int gemmBlocks = (n + 127) / 128;
    // layer 1: hs = (x@W1)*dinv (bf16) ; g = relu(dinv*(agg(hs)+hs) + b1) (bf16)
    k_gemm_mfma<256><<<gemmBlocks, 256, 0, stream>>>(x, wt1hi, wt1lo, dinv, bufH, n);
    k_agg<true, true><<<aggBlocks, 256, 0, stream>>>(bufH, dinv, offs, csr, b1, bufG, n);
    // layer 2: hs = (g@W2)*dinv (bf16) ; out = dinv*(agg(hs)+hs) + b2 (f32)
    k_gemm_bf16<128><<<gemmBlocks, 256, 0, stream>>>(bufG, wt2hi, wt2lo, dinv, bufH, n);
    k_agg<false, false><<<aggBlocks, 256, 0, stream>>>(bufH, dinv, offs, csr, b2, d_out, n);
}